// Round 3
// baseline (556.302 us; speedup 1.0000x reference)
//
#include <hip/hip_runtime.h>
#include <hip/hip_bf16.h>
#include <math.h>

#define NE 80000
#define NN 10000
#define NG 16
#define MP_NORM 0.31622776601683794f   // 1/sqrt(10)
#define RBF_NORM 0.60302268915552724f  // sqrt(2/5.5)

// monomial tables: index -> (lx,ly,lz), l
__constant__ int c_mx[20] = {0, 1,0,0, 2,1,1,0,0,0, 3,2,2,1,1,1,0,0,0,0};
__constant__ int c_my[20] = {0, 0,1,0, 0,1,0,2,1,0, 0,1,0,2,1,0,3,2,1,0};
__constant__ int c_mz[20] = {0, 0,0,1, 0,0,1,0,1,2, 0,0,1,0,1,2,0,1,2,3};

__device__ __forceinline__ int l_of_a(int a) {
    return (a >= 10) ? 3 : ((a >= 4) ? 2 : ((a >= 1) ? 1 : 0));
}

// ---------------------------------------------------------------------------
// Pass 1: per-edge featurization, fold W_rt into the radial vector, scatter
// A[n,s,a,c] (+= radt[l_a,s]*ang[a]*code[c]) via atomics. One wave per edge.
// ---------------------------------------------------------------------------
__global__ __launch_bounds__(256) void k_edge1(
    const float* __restrict__ pos, const int* __restrict__ ntype,
    const int* __restrict__ src, const int* __restrict__ dst,
    const float* __restrict__ shifts, const float* __restrict__ Wemb,
    const float* __restrict__ freqs, const float* __restrict__ W_rt,
    float* __restrict__ A)
{
    __shared__ float sh[4][56];   // per wave: ang[0..19], code[20..28], radt[29..52]
    const int wave = threadIdx.x >> 6, lane = threadIdx.x & 63;
    const int e = blockIdx.x * 4 + wave;
    float* S = sh[wave];
    float fc = 0.f;
    int dn = 0;
    if (e < NE) {
        const int sn = src[e];
        dn = dst[e];
        const float vx = pos[3*dn+0] - pos[3*sn+0] + shifts[3*e+0];
        const float vy = pos[3*dn+1] - pos[3*sn+1] + shifts[3*e+1];
        const float vz = pos[3*dn+2] - pos[3*sn+2] + shifts[3*e+2];
        const float r = sqrtf(vx*vx + vy*vy + vz*vz) + 1e-9f;
        const float u = r * (1.0f / 5.5f);
        if (u < 1.0f) {
            const float u2 = u*u, u3 = u2*u, u6 = u3*u3;
            fc = 1.0f - 28.0f*u6 + 48.0f*u6*u - 21.0f*u6*u2;
            const float inv = 1.0f / r;
            const float ux = vx*inv, uy = vy*inv, uz = vz*inv;
            float rb[6];
            #pragma unroll
            for (int k = 0; k < 6; k++)
                rb[k] = RBF_NORM * sinf(r * freqs[k]) * inv * fc;
            if (lane < 20) {
                const int lx = c_mx[lane], ly = c_my[lane], lz = c_mz[lane];
                float v = 1.f;
                for (int i = 0; i < lx; i++) v *= ux;
                for (int i = 0; i < ly; i++) v *= uy;
                for (int i = 0; i < lz; i++) v *= uz;
                S[lane] = v;
            } else if (lane < 29) {
                const int c = lane - 20;
                S[lane] = Wemb[3*ntype[sn] + c/3] * Wemb[3*ntype[dn] + c%3];
            } else if (lane >= 32 && lane < 56) {
                const int j = lane - 32, l = j / 6, s2 = j % 6;
                float acc = 0.f;
                #pragma unroll
                for (int r2 = 0; r2 < 6; r2++)
                    acc += rb[r2] * W_rt[(l*6 + r2)*6 + s2];
                S[29 + j] = acc;
            }
        }
    }
    __syncthreads();
    if (e < NE && fc != 0.f) {
        float* base = A + (long)dn * 1080;
        for (int i = lane; i < 1080; i += 64) {
            const int s2 = i / 180, rem = i - s2*180;
            const int a = rem / 9, c = rem - a*9;
            const float val = S[29 + l_of_a(a)*6 + s2] * S[a] * S[20 + c];
            atomicAdd(base + i, val);
        }
    }
}

// ---------------------------------------------------------------------------
// Pass 2: scatter both messages in one atomic stream:
// Q[dst,s,a,c] += radtB[l,s]*ang[a]*code[c]*chi[src,c] + A[src,s,a,c]*radtA[l,s]
// ---------------------------------------------------------------------------
__global__ __launch_bounds__(256) void k_edge2(
    const float* __restrict__ pos, const int* __restrict__ ntype,
    const int* __restrict__ src, const int* __restrict__ dst,
    const float* __restrict__ shifts, const float* __restrict__ Wemb,
    const float* __restrict__ freqs, const float* __restrict__ W_rt,
    const float* __restrict__ W_Ar, const float* __restrict__ chi,
    const float* __restrict__ A, float* __restrict__ Q)
{
    __shared__ float sh[4][80];   // ang[0..19], codechi[20..28], radtB[29..52], radtA[53..76]
    const int wave = threadIdx.x >> 6, lane = threadIdx.x & 63;
    const int e = blockIdx.x * 4 + wave;
    float* S = sh[wave];
    float fc = 0.f;
    int dn = 0, sn = 0;
    if (e < NE) {
        sn = src[e];
        dn = dst[e];
        const float vx = pos[3*dn+0] - pos[3*sn+0] + shifts[3*e+0];
        const float vy = pos[3*dn+1] - pos[3*sn+1] + shifts[3*e+1];
        const float vz = pos[3*dn+2] - pos[3*sn+2] + shifts[3*e+2];
        const float r = sqrtf(vx*vx + vy*vy + vz*vz) + 1e-9f;
        const float u = r * (1.0f / 5.5f);
        if (u < 1.0f) {
            const float u2 = u*u, u3 = u2*u, u6 = u3*u3;
            fc = 1.0f - 28.0f*u6 + 48.0f*u6*u - 21.0f*u6*u2;
            const float inv = 1.0f / r;
            const float ux = vx*inv, uy = vy*inv, uz = vz*inv;
            float rb[6];
            #pragma unroll
            for (int k = 0; k < 6; k++)
                rb[k] = RBF_NORM * sinf(r * freqs[k]) * inv * fc;
            if (lane < 20) {
                const int lx = c_mx[lane], ly = c_my[lane], lz = c_mz[lane];
                float v = 1.f;
                for (int i = 0; i < lx; i++) v *= ux;
                for (int i = 0; i < ly; i++) v *= uy;
                for (int i = 0; i < lz; i++) v *= uz;
                S[lane] = v;
            } else if (lane < 29) {
                const int c = lane - 20;
                S[lane] = Wemb[3*ntype[sn] + c/3] * Wemb[3*ntype[dn] + c%3]
                        * chi[sn*9 + c];
            } else if (lane >= 32 && lane < 56) {
                const int j = lane - 32, l = j / 6, s2 = j % 6;
                float accB = 0.f, accA = 0.f;
                #pragma unroll
                for (int r2 = 0; r2 < 6; r2++) {
                    accB += rb[r2] * W_rt[(l*6 + r2)*6 + s2];
                    accA += rb[r2] * W_Ar[(l*6 + r2)*6 + s2];
                }
                S[29 + j] = accB;
                S[53 + j] = accA;
            }
        }
    }
    __syncthreads();
    if (e < NE && fc != 0.f) {
        const float* asrc = A + (long)sn * 1080;
        float* base = Q + (long)dn * 1080;
        for (int i = lane; i < 1080; i += 64) {
            const int s2 = i / 180, rem = i - s2*180;
            const int a = rem / 9, c = rem - a*9;
            const int l6 = l_of_a(a)*6 + s2;
            const float val = S[29 + l6] * S[a] * S[20 + c] + asrc[i] * S[53 + l6];
            atomicAdd(base + i, val);
        }
    }
}

// ---------------------------------------------------------------------------
// Symmetrize: A[n,s,0..19,c] -> B[n,s,0..5,c]
// ---------------------------------------------------------------------------
__global__ __launch_bounds__(256) void k_symm(const float* __restrict__ A,
                                              float* __restrict__ B)
{
    const int t = blockIdx.x * 256 + threadIdx.x;
    if (t >= NN * 54) return;
    const int c = t % 9, s2 = (t / 9) % 6, n = t / 54;
    const float* a = A + (long)n*1080 + s2*180 + c;
    float v[20];
    #pragma unroll
    for (int i = 0; i < 20; i++) v[i] = a[i*9];
    const float o0 = v[0];
    const float o1 = v[1]*v[1] + v[2]*v[2] + v[3]*v[3];
    const float o2 = v[4]*v[4] + 2.f*v[5]*v[5] + 2.f*v[6]*v[6]
                   + v[7]*v[7] + 2.f*v[8]*v[8] + v[9]*v[9];
    const float o3 = v[10]*v[10] + 3.f*v[11]*v[11] + 3.f*v[12]*v[12]
                   + 3.f*v[13]*v[13] + 6.f*v[14]*v[14] + 3.f*v[15]*v[15]
                   + v[16]*v[16] + 3.f*v[17]*v[17] + 3.f*v[18]*v[18] + v[19]*v[19];
    const float o4 = v[1]*v[1]*v[4] + 2.f*v[1]*v[2]*v[5] + 2.f*v[1]*v[3]*v[6]
                   + 2.f*v[2]*v[1]*v[5] + v[2]*v[2]*v[7] + 2.f*v[2]*v[3]*v[8]
                   + 2.f*v[3]*v[1]*v[6] + 2.f*v[3]*v[2]*v[8] + v[3]*v[3]*v[9];
    const float o5 =
        v[1]*(v[4]*v[10] + 3.f*v[5]*v[11] + 3.f*v[6]*v[12] + 3.f*v[7]*v[13]
              + 6.f*v[8]*v[14] + 3.f*v[9]*v[15])
      + v[2]*(3.f*v[4]*v[11] + 3.f*v[5]*v[13] + 6.f*v[6]*v[14] + v[7]*v[16]
              + 3.f*v[8]*v[17] + 3.f*v[9]*v[18])
      + v[3]*(3.f*v[4]*v[12] + 6.f*v[5]*v[14] + 3.f*v[6]*v[15] + 3.f*v[7]*v[17]
              + 3.f*v[8]*v[18] + v[9]*v[19]);
    float* b = B + (long)n*324 + s2*54 + c;
    b[0]  = o0;
    b[9]  = o1;
    b[18] = o2;
    b[27] = o3;
    b[36] = o4;
    b[45] = o5;
}

// chi[n,c'] = B[n,:].W_chi[:,c']
__global__ __launch_bounds__(256) void k_chi(const float* __restrict__ B,
                                             const float* __restrict__ W_chi,
                                             float* __restrict__ chi)
{
    const int t = blockIdx.x * 256 + threadIdx.x;
    if (t >= NN * 9) return;
    const int cp = t % 9, n = t / 9;
    const float* b = B + (long)n * 324;
    float acc = 0.f;
    for (int j = 0; j < 324; j++) acc += b[j] * W_chi[j*9 + cp];
    chi[t] = acc;
}

// Q[n,s,a,c] = Q[n,s,a,c]*MP_NORM + sum_s' A[n,s',a,c]*W_mem[l_a,s',s]
__global__ __launch_bounds__(256) void k_comb(const float* __restrict__ A,
                                              const float* __restrict__ W_mem,
                                              float* __restrict__ Q)
{
    const int t = blockIdx.x * 256 + threadIdx.x;
    if (t >= NN * 180) return;
    const int c = t % 9, a = (t / 9) % 20, n = t / 180;
    const int l = l_of_a(a);
    const float* ap = A + (long)n*1080 + a*9 + c;
    float* qp = Q + (long)n*1080 + a*9 + c;
    float av[6], qv[6];
    #pragma unroll
    for (int s = 0; s < 6; s++) { av[s] = ap[s*180]; qv[s] = qp[s*180]; }
    #pragma unroll
    for (int s = 0; s < 6; s++) {
        float m = 0.f;
        #pragma unroll
        for (int sp = 0; sp < 6; sp++) m += av[sp] * W_mem[(l*6 + sp)*6 + s];
        qp[s*180] = qv[s] * MP_NORM + m;
    }
}

// ---------------------------------------------------------------------------
// MLP readout as a tiled SGEMM: feats[10000,648] @ W1[648,64] with K-order
// permuted to (all-B, all-B2); 64x64 output tile per 256-thread block;
// each thread computes a 4x4 register tile. Layers 2/3 + segment-sum fused.
// ---------------------------------------------------------------------------
#define KT 54   // 648 = 12 * 54
__global__ __launch_bounds__(256) void k_mlp(
    const float* __restrict__ B, const float* __restrict__ B2,
    const float* __restrict__ W1, const float* __restrict__ b1,
    const float* __restrict__ W2, const float* __restrict__ b2,
    const float* __restrict__ W3, const float* __restrict__ b3,
    const int* __restrict__ batch, float* __restrict__ out)
{
    __shared__ float As[KT][68];     // K-chunk x 64 nodes (pad 68)
    __shared__ float Ws[KT][64];     // K-chunk x 64 cols
    __shared__ float h1s[64][68];    // nodes x 64 hidden (pad 68)
    __shared__ float h2s[64][33];    // nodes x 32 hidden (pad 33)
    const int tid = threadIdx.x;
    const int nb = blockIdx.x * 64;
    const int tx = tid & 15, ty = tid >> 4;   // col group, node group
    float acc[4][4] = {};
    for (int k0 = 0; k0 < 648; k0 += KT) {
        for (int idx = tid; idx < KT * 64; idx += 256) {
            const int kk = idx >> 6, o = idx & 63;
            const int k = k0 + kk;
            const int row = (k < 324) ? (2 * k) : (2 * (k - 324) + 1);
            Ws[kk][o] = W1[row * 64 + o];
        }
        for (int idx = tid; idx < 64 * KT; idx += 256) {
            const int m = idx / KT, kk = idx - m * KT;
            const int n = nb + m, k = k0 + kk;
            float v = 0.f;
            if (n < NN)
                v = (k < 324) ? B[(long)n * 324 + k] : B2[(long)n * 324 + (k - 324)];
            As[kk][m] = v;
        }
        __syncthreads();
        #pragma unroll 18
        for (int kk = 0; kk < KT; kk++) {
            const float4 a = *(const float4*)&As[kk][4 * ty];
            const float4 w = *(const float4*)&Ws[kk][4 * tx];
            acc[0][0] += a.x * w.x; acc[0][1] += a.x * w.y;
            acc[0][2] += a.x * w.z; acc[0][3] += a.x * w.w;
            acc[1][0] += a.y * w.x; acc[1][1] += a.y * w.y;
            acc[1][2] += a.y * w.z; acc[1][3] += a.y * w.w;
            acc[2][0] += a.z * w.x; acc[2][1] += a.z * w.y;
            acc[2][2] += a.z * w.z; acc[2][3] += a.z * w.w;
            acc[3][0] += a.w * w.x; acc[3][1] += a.w * w.y;
            acc[3][2] += a.w * w.z; acc[3][3] += a.w * w.w;
        }
        __syncthreads();
    }
    // silu(acc + b1) -> h1s
    const float4 bb = *(const float4*)&b1[4 * tx];
    #pragma unroll
    for (int m = 0; m < 4; m++) {
        float4 h;
        h.x = acc[m][0] + bb.x; h.y = acc[m][1] + bb.y;
        h.z = acc[m][2] + bb.z; h.w = acc[m][3] + bb.w;
        h.x = h.x / (1.f + expf(-h.x)); h.y = h.y / (1.f + expf(-h.y));
        h.z = h.z / (1.f + expf(-h.z)); h.w = h.w / (1.f + expf(-h.w));
        *(float4*)&h1s[4 * ty + m][4 * tx] = h;
    }
    __syncthreads();
    // layer 2: h2[n][oo], thread handles oo = tid&31 for 8 nodes
    {
        const int oo = tid & 31, ng = tid >> 5;   // ng in [0,8)
        float g[8];
        #pragma unroll
        for (int i = 0; i < 8; i++) g[i] = b2[oo];
        for (int k = 0; k < 64; k++) {
            const float w = W2[k * 32 + oo];
            #pragma unroll
            for (int i = 0; i < 8; i++) g[i] += h1s[ng + 8 * i][k] * w;
        }
        #pragma unroll
        for (int i = 0; i < 8; i++)
            h2s[ng + 8 * i][oo] = g[i] / (1.f + expf(-g[i]));
    }
    __syncthreads();
    // layer 3 + segment sum
    if (tid < 64) {
        const int n = nb + tid;
        if (n < NN) {
            float a3 = b3[0];
            #pragma unroll
            for (int k = 0; k < 32; k++) a3 += h2s[tid][k] * W3[k];
            atomicAdd(out + batch[n], a3);
        }
    }
}

extern "C" void kernel_launch(void* const* d_in, const int* in_sizes, int n_in,
                              void* d_out, int out_size, void* d_ws, size_t ws_size,
                              hipStream_t stream)
{
    const float* pos    = (const float*)d_in[0];
    const int*   ntype  = (const int*)  d_in[1];
    const int*   src    = (const int*)  d_in[2];
    const int*   dst    = (const int*)  d_in[3];
    const float* shifts = (const float*)d_in[4];
    const int*   batch  = (const int*)  d_in[5];
    const float* Wemb   = (const float*)d_in[6];
    const float* freqs  = (const float*)d_in[7];
    const float* W_rt   = (const float*)d_in[8];
    const float* W_mem  = (const float*)d_in[9];
    const float* W_Ar   = (const float*)d_in[10];
    const float* W_chi  = (const float*)d_in[11];
    const float* W1     = (const float*)d_in[12];
    const float* b1     = (const float*)d_in[13];
    const float* W2     = (const float*)d_in[14];
    const float* b2     = (const float*)d_in[15];
    const float* W3     = (const float*)d_in[16];
    const float* b3     = (const float*)d_in[17];

    float* ws  = (float*)d_ws;
    float* A   = ws;                 // [NN,1080]
    float* Q   = A  + (size_t)NN * 1080;   // [NN,1080]
    float* B   = Q  + (size_t)NN * 1080;   // [NN,324]
    float* B2  = B  + (size_t)NN * 324;    // [NN,324]
    float* chi = B2 + (size_t)NN * 324;    // [NN,9]

    hipMemsetAsync(A, 0, (size_t)NN * 1080 * sizeof(float), stream);
    hipMemsetAsync(Q, 0, (size_t)NN * 1080 * sizeof(float), stream);
    hipMemsetAsync(d_out, 0, (size_t)out_size * sizeof(float), stream);

    k_edge1<<<NE/4, 256, 0, stream>>>(pos, ntype, src, dst, shifts, Wemb, freqs,
                                      W_rt, A);
    k_symm<<<(NN*54 + 255)/256, 256, 0, stream>>>(A, B);
    k_chi<<<(NN*9 + 255)/256, 256, 0, stream>>>(B, W_chi, chi);
    k_edge2<<<NE/4, 256, 0, stream>>>(pos, ntype, src, dst, shifts, Wemb, freqs,
                                      W_rt, W_Ar, chi, A, Q);
    k_comb<<<(NN*180 + 255)/256, 256, 0, stream>>>(A, W_mem, Q);
    k_symm<<<(NN*54 + 255)/256, 256, 0, stream>>>(Q, B2);
    k_mlp<<<(NN + 63)/64, 256, 0, stream>>>(B, B2, W1, b1, W2, b2, W3, b3, batch,
                                            (float*)d_out);
}

// Round 4
// 475.962 us; speedup vs baseline: 1.1688x; 1.1688x over previous
//
#include <hip/hip_runtime.h>
#include <hip/hip_bf16.h>
#include <math.h>

#define NE 80000
#define NN 10000
#define NG 16
#define MP_NORM 0.31622776601683794f   // 1/sqrt(10)
#define RBF_NORM 0.60302268915552724f  // sqrt(2/5.5)

// monomial tables: index -> (lx,ly,lz), l
__constant__ int c_mx[20] = {0, 1,0,0, 2,1,1,0,0,0, 3,2,2,1,1,1,0,0,0,0};
__constant__ int c_my[20] = {0, 0,1,0, 0,1,0,2,1,0, 0,1,0,2,1,0,3,2,1,0};
__constant__ int c_mz[20] = {0, 0,0,1, 0,0,1,0,1,2, 0,0,1,0,1,2,0,1,2,3};

__device__ __forceinline__ int l_of_a(int a) {
    return (a >= 10) ? 3 : ((a >= 4) ? 2 : ((a >= 1) ? 1 : 0));
}

// symmetrize one node's 1080-vector (in LDS) -> 324 outputs (global row)
__device__ __forceinline__ void symm_from_lds(const float* Als, float* brow,
                                              int lane) {
    if (lane >= 54) return;
    const int s2 = lane / 9, c = lane - s2 * 9;
    const float* a = Als + s2 * 180 + c;
    float v[20];
    #pragma unroll
    for (int i = 0; i < 20; i++) v[i] = a[i * 9];
    const float o0 = v[0];
    const float o1 = v[1]*v[1] + v[2]*v[2] + v[3]*v[3];
    const float o2 = v[4]*v[4] + 2.f*v[5]*v[5] + 2.f*v[6]*v[6]
                   + v[7]*v[7] + 2.f*v[8]*v[8] + v[9]*v[9];
    const float o3 = v[10]*v[10] + 3.f*v[11]*v[11] + 3.f*v[12]*v[12]
                   + 3.f*v[13]*v[13] + 6.f*v[14]*v[14] + 3.f*v[15]*v[15]
                   + v[16]*v[16] + 3.f*v[17]*v[17] + 3.f*v[18]*v[18] + v[19]*v[19];
    const float o4 = v[1]*v[1]*v[4] + 2.f*v[1]*v[2]*v[5] + 2.f*v[1]*v[3]*v[6]
                   + 2.f*v[2]*v[1]*v[5] + v[2]*v[2]*v[7] + 2.f*v[2]*v[3]*v[8]
                   + 2.f*v[3]*v[1]*v[6] + 2.f*v[3]*v[2]*v[8] + v[3]*v[3]*v[9];
    const float o5 =
        v[1]*(v[4]*v[10] + 3.f*v[5]*v[11] + 3.f*v[6]*v[12] + 3.f*v[7]*v[13]
              + 6.f*v[8]*v[14] + 3.f*v[9]*v[15])
      + v[2]*(3.f*v[4]*v[11] + 3.f*v[5]*v[13] + 6.f*v[6]*v[14] + v[7]*v[16]
              + 3.f*v[8]*v[17] + 3.f*v[9]*v[18])
      + v[3]*(3.f*v[4]*v[12] + 6.f*v[5]*v[14] + 3.f*v[6]*v[15] + 3.f*v[7]*v[17]
              + 3.f*v[8]*v[18] + v[9]*v[19]);
    float* b = brow + s2 * 54 + c;
    b[0]  = o0;
    b[9]  = o1;
    b[18] = o2;
    b[27] = o3;
    b[36] = o4;
    b[45] = o5;
}

// ---------------------------------------------------------------------------
// CSR build: histogram of dst over fc-active edges, scan, fill.
// ---------------------------------------------------------------------------
__global__ __launch_bounds__(256) void k_hist(
    const float* __restrict__ pos, const int* __restrict__ src,
    const int* __restrict__ dst, const float* __restrict__ shifts,
    int* __restrict__ indeg)
{
    const int e = blockIdx.x * 256 + threadIdx.x;
    if (e >= NE) return;
    const int sn = src[e], dn = dst[e];
    const float vx = pos[3*dn+0] - pos[3*sn+0] + shifts[3*e+0];
    const float vy = pos[3*dn+1] - pos[3*sn+1] + shifts[3*e+1];
    const float vz = pos[3*dn+2] - pos[3*sn+2] + shifts[3*e+2];
    const float r = sqrtf(vx*vx + vy*vy + vz*vz) + 1e-9f;
    if (r * (1.0f / 5.5f) < 1.0f) atomicAdd(&indeg[dn], 1);
}

__global__ __launch_bounds__(256) void k_scan(const int* __restrict__ indeg,
                                              int* __restrict__ offs)
{
    __shared__ int part[256];
    const int t = threadIdx.x;
    int s = 0;
    for (int i = t * 40; i < t * 40 + 40; i++)
        if (i < NN) s += indeg[i];
    part[t] = s;
    __syncthreads();
    if (t == 0) {
        int run = 0;
        for (int i = 0; i < 256; i++) { int v = part[i]; part[i] = run; run += v; }
    }
    __syncthreads();
    int run = part[t];
    for (int i = t * 40; i < t * 40 + 40; i++) {
        if (i < NN) { offs[i] = run; run += indeg[i]; }
    }
}

__global__ __launch_bounds__(256) void k_fill(
    const float* __restrict__ pos, const int* __restrict__ src,
    const int* __restrict__ dst, const float* __restrict__ shifts,
    const int* __restrict__ offs, int* __restrict__ cursor,
    int* __restrict__ elist)
{
    const int e = blockIdx.x * 256 + threadIdx.x;
    if (e >= NE) return;
    const int sn = src[e], dn = dst[e];
    const float vx = pos[3*dn+0] - pos[3*sn+0] + shifts[3*e+0];
    const float vy = pos[3*dn+1] - pos[3*sn+1] + shifts[3*e+1];
    const float vz = pos[3*dn+2] - pos[3*sn+2] + shifts[3*e+2];
    const float r = sqrtf(vx*vx + vy*vy + vz*vz) + 1e-9f;
    if (r * (1.0f / 5.5f) < 1.0f) {
        const int p = offs[dn] + atomicAdd(&cursor[dn], 1);
        elist[p] = e;
    }
}

// ---------------------------------------------------------------------------
// Pass 1, gather form: one wave per node. Accumulate A[n] in registers over
// incoming edges (no atomics), write A, symmetrize inline -> B.
// ---------------------------------------------------------------------------
__global__ __launch_bounds__(64) void k_node1(
    const float* __restrict__ pos, const int* __restrict__ ntype,
    const int* __restrict__ srcArr, const float* __restrict__ shifts,
    const float* __restrict__ Wemb, const float* __restrict__ freqs,
    const float* __restrict__ W_rt, const int* __restrict__ offs,
    const int* __restrict__ indeg, const int* __restrict__ elist,
    float* __restrict__ A, float* __restrict__ Bf)
{
    __shared__ float eS[80];     // ang[0..19], code[20..28], radt[29..52]
    __shared__ float Als[1080];
    const int n = blockIdx.x, lane = threadIdx.x;
    int ridx[17], aidx[17], cidx[17];
    float acc[17];
    #pragma unroll
    for (int k = 0; k < 17; k++) {
        acc[k] = 0.f;
        const int i = lane + 64 * k;
        const int ii = (i < 1080) ? i : 0;
        const int s2 = ii / 180, rem = ii - s2 * 180;
        const int a = rem / 9, c = rem - a * 9;
        ridx[k] = 29 + l_of_a(a) * 6 + s2; aidx[k] = a; cidx[k] = 20 + c;
    }
    const float px = pos[3*n], py = pos[3*n+1], pz = pos[3*n+2];
    const float ed0 = Wemb[3*ntype[n]], ed1 = Wemb[3*ntype[n]+1],
                ed2 = Wemb[3*ntype[n]+2];
    float fr[6];
    #pragma unroll
    for (int q = 0; q < 6; q++) fr[q] = freqs[q];
    // per-lane W_rt row hoisted (constant across edges)
    float wrt[6];
    if (lane >= 32 && lane < 56) {
        const int j = lane - 32, l = j / 6, s2 = j % 6;
        #pragma unroll
        for (int q = 0; q < 6; q++) wrt[q] = W_rt[(l*6 + q)*6 + s2];
    }
    const int e0 = offs[n], cnt = indeg[n];
    int e_next = (cnt > 0) ? elist[e0] : 0;
    int sn_next = (cnt > 0) ? srcArr[e_next] : 0;
    for (int t = 0; t < cnt; t++) {
        const int e = e_next, sn = sn_next;
        if (t + 1 < cnt) { e_next = elist[e0 + t + 1]; sn_next = srcArr[e_next]; }
        const float vx = px - pos[3*sn+0] + shifts[3*e+0];
        const float vy = py - pos[3*sn+1] + shifts[3*e+1];
        const float vz = pz - pos[3*sn+2] + shifts[3*e+2];
        const float r = sqrtf(vx*vx + vy*vy + vz*vz) + 1e-9f;
        const float u = r * (1.0f / 5.5f);
        const float u2 = u*u, u3 = u2*u, u6 = u3*u3;
        const float fcv = 1.0f - 28.0f*u6 + 48.0f*u6*u - 21.0f*u6*u2;
        const float inv = 1.0f / r;
        float rb[6];
        #pragma unroll
        for (int q = 0; q < 6; q++)
            rb[q] = RBF_NORM * __sinf(r * fr[q]) * inv * fcv;
        if (lane < 20) {
            const float ux = vx*inv, uy = vy*inv, uz = vz*inv;
            const int lx = c_mx[lane], ly = c_my[lane], lz = c_mz[lane];
            float v = 1.f;
            for (int i = 0; i < lx; i++) v *= ux;
            for (int i = 0; i < ly; i++) v *= uy;
            for (int i = 0; i < lz; i++) v *= uz;
            eS[lane] = v;
        } else if (lane < 29) {
            const int c = lane - 20, m = c % 3;
            const float ed = (m == 0) ? ed0 : ((m == 1) ? ed1 : ed2);
            eS[lane] = Wemb[3*ntype[sn] + c/3] * ed;
        } else if (lane >= 32 && lane < 56) {
            float s = 0.f;
            #pragma unroll
            for (int q = 0; q < 6; q++) s += rb[q] * wrt[q];
            eS[lane - 3] = s;   // 29 + (lane-32)
        }
        __syncthreads();
        #pragma unroll
        for (int k = 0; k < 17; k++)
            acc[k] += eS[ridx[k]] * eS[aidx[k]] * eS[cidx[k]];
        __syncthreads();
    }
    #pragma unroll
    for (int k = 0; k < 17; k++) {
        const int i = lane + 64 * k;
        if (i < 1080) { A[(long)n*1080 + i] = acc[k]; Als[i] = acc[k]; }
    }
    __syncthreads();
    symm_from_lds(Als, Bf + (long)n * 324, lane);
}

// chi[n,c'] = B[n,:] . W_chi[:,c']
__global__ __launch_bounds__(256) void k_chi(const float* __restrict__ Bf,
                                             const float* __restrict__ W_chi,
                                             float* __restrict__ chi)
{
    const int t = blockIdx.x * 256 + threadIdx.x;
    if (t >= NN * 9) return;
    const int cp = t % 9, n = t / 9;
    const float* b = Bf + (long)n * 324;
    float s = 0.f;
    #pragma unroll 4
    for (int j = 0; j < 324; j += 4) {
        const float4 bv = *(const float4*)(b + j);
        s += bv.x * W_chi[(j+0)*9 + cp] + bv.y * W_chi[(j+1)*9 + cp]
           + bv.z * W_chi[(j+2)*9 + cp] + bv.w * W_chi[(j+3)*9 + cp];
    }
    chi[t] = s;
}

// ---------------------------------------------------------------------------
// Pass 2, gather form: one wave per node. Accumulate msg_B + msg_Ar in
// registers, add memory term (W_mem x A[n]), MP_NORM, symmetrize -> B2.
// ---------------------------------------------------------------------------
__global__ __launch_bounds__(64) void k_node2(
    const float* __restrict__ pos, const int* __restrict__ ntype,
    const int* __restrict__ srcArr, const float* __restrict__ shifts,
    const float* __restrict__ Wemb, const float* __restrict__ freqs,
    const float* __restrict__ W_rt, const float* __restrict__ W_Ar,
    const float* __restrict__ W_mem, const int* __restrict__ offs,
    const int* __restrict__ indeg, const int* __restrict__ elist,
    const float* __restrict__ chi, const float* __restrict__ A,
    float* __restrict__ B2f)
{
    __shared__ float eS[80];     // ang, codechi[20..28], radtB[29..52], radtA[53..76]
    __shared__ float Als[1080];
    __shared__ float Qls[1080];
    __shared__ float Wm[144];
    const int n = blockIdx.x, lane = threadIdx.x;
    #pragma unroll
    for (int k = 0; k < 17; k++) {
        const int i = lane + 64 * k;
        if (i < 1080) Als[i] = A[(long)n*1080 + i];
    }
    Wm[lane] = W_mem[lane];
    Wm[lane + 64] = W_mem[lane + 64];
    if (lane < 16) Wm[lane + 128] = W_mem[lane + 128];
    int ridx[17], aidx[17], cidx[17];
    float acc[17];
    #pragma unroll
    for (int k = 0; k < 17; k++) {
        acc[k] = 0.f;
        const int i = lane + 64 * k;
        const int ii = (i < 1080) ? i : 0;
        const int s2 = ii / 180, rem = ii - s2 * 180;
        const int a = rem / 9, c = rem - a * 9;
        ridx[k] = 29 + l_of_a(a) * 6 + s2; aidx[k] = a; cidx[k] = 20 + c;
    }
    const float px = pos[3*n], py = pos[3*n+1], pz = pos[3*n+2];
    const float ed0 = Wemb[3*ntype[n]], ed1 = Wemb[3*ntype[n]+1],
                ed2 = Wemb[3*ntype[n]+2];
    float fr[6];
    #pragma unroll
    for (int q = 0; q < 6; q++) fr[q] = freqs[q];
    float wrtB[6], wrtA[6];
    if (lane >= 32 && lane < 56) {
        const int j = lane - 32, l = j / 6, s2 = j % 6;
        #pragma unroll
        for (int q = 0; q < 6; q++) {
            wrtB[q] = W_rt[(l*6 + q)*6 + s2];
            wrtA[q] = W_Ar[(l*6 + q)*6 + s2];
        }
    }
    __syncthreads();
    const int e0 = offs[n], cnt = indeg[n];
    int e_next = (cnt > 0) ? elist[e0] : 0;
    int sn_next = (cnt > 0) ? srcArr[e_next] : 0;
    for (int t = 0; t < cnt; t++) {
        const int e = e_next, sn = sn_next;
        if (t + 1 < cnt) { e_next = elist[e0 + t + 1]; sn_next = srcArr[e_next]; }
        const float vx = px - pos[3*sn+0] + shifts[3*e+0];
        const float vy = py - pos[3*sn+1] + shifts[3*e+1];
        const float vz = pz - pos[3*sn+2] + shifts[3*e+2];
        const float r = sqrtf(vx*vx + vy*vy + vz*vz) + 1e-9f;
        const float u = r * (1.0f / 5.5f);
        const float u2 = u*u, u3 = u2*u, u6 = u3*u3;
        const float fcv = 1.0f - 28.0f*u6 + 48.0f*u6*u - 21.0f*u6*u2;
        const float inv = 1.0f / r;
        float rb[6];
        #pragma unroll
        for (int q = 0; q < 6; q++)
            rb[q] = RBF_NORM * __sinf(r * fr[q]) * inv * fcv;
        if (lane < 20) {
            const float ux = vx*inv, uy = vy*inv, uz = vz*inv;
            const int lx = c_mx[lane], ly = c_my[lane], lz = c_mz[lane];
            float v = 1.f;
            for (int i = 0; i < lx; i++) v *= ux;
            for (int i = 0; i < ly; i++) v *= uy;
            for (int i = 0; i < lz; i++) v *= uz;
            eS[lane] = v;
        } else if (lane < 29) {
            const int c = lane - 20, m = c % 3;
            const float ed = (m == 0) ? ed0 : ((m == 1) ? ed1 : ed2);
            eS[lane] = Wemb[3*ntype[sn] + c/3] * ed * chi[sn*9 + c];
        } else if (lane >= 32 && lane < 56) {
            float sB = 0.f, sA = 0.f;
            #pragma unroll
            for (int q = 0; q < 6; q++) { sB += rb[q]*wrtB[q]; sA += rb[q]*wrtA[q]; }
            eS[lane - 3]  = sB;   // 29 + j
            eS[lane + 21] = sA;   // 53 + j
        }
        __syncthreads();
        const float* asrc = A + (long)sn * 1080;
        #pragma unroll
        for (int k = 0; k < 17; k++) {
            const int i = lane + 64 * k;
            if (i < 1080)
                acc[k] += eS[ridx[k]] * eS[aidx[k]] * eS[cidx[k]]
                        + asrc[i] * eS[ridx[k] + 24];
        }
        __syncthreads();
    }
    // memory term + MP_NORM -> Qls
    #pragma unroll
    for (int k = 0; k < 17; k++) {
        const int i = lane + 64 * k;
        if (i < 1080) {
            const int l6 = ridx[k] - 29;
            const int l = l6 / 6, s2v = l6 - 6 * l;
            const int rem = aidx[k] * 9 + (cidx[k] - 20);
            float m = 0.f;
            #pragma unroll
            for (int sp = 0; sp < 6; sp++)
                m += Als[sp*180 + rem] * Wm[l*36 + sp*6 + s2v];
            Qls[i] = acc[k] * MP_NORM + m;
        }
    }
    __syncthreads();
    symm_from_lds(Qls, B2f + (long)n * 324, lane);
}

// ---------------------------------------------------------------------------
// MLP readout: 16 nodes/block, no LDS in hot loop, feats broadcast-loaded
// from global, W1 coalesced; 10 vmem + 32 FMA per body. Layers 2/3 fused.
// ---------------------------------------------------------------------------
__global__ __launch_bounds__(256) void k_mlp(
    const float* __restrict__ Bf, const float* __restrict__ B2f,
    const float* __restrict__ W1, const float* __restrict__ b1,
    const float* __restrict__ W2, const float* __restrict__ b2,
    const float* __restrict__ W3, const float* __restrict__ b3,
    const int* __restrict__ batch, float* __restrict__ out)
{
    __shared__ float h1s[16][68];
    __shared__ float h2s[16][33];
    const int tid = threadIdx.x;
    const int tx = tid & 15, ty = tid >> 4;
    const int nb = blockIdx.x * 16;
    const float* bRow  = Bf  + (long)(nb + ty) * 324;
    const float* b2Row = B2f + (long)(nb + ty) * 324;
    float a0 = 0.f, a1 = 0.f, a2 = 0.f, a3 = 0.f;
    #pragma unroll 2
    for (int jj = 0; jj < 324; jj += 4) {
        const float4 fB  = *(const float4*)(bRow  + jj);
        const float4 fB2 = *(const float4*)(b2Row + jj);
        const float* wp = W1 + (size_t)(2 * jj) * 64 + 4 * tx;
        const float4 w0 = *(const float4*)(wp + 0*64);
        const float4 w1 = *(const float4*)(wp + 1*64);
        const float4 w2 = *(const float4*)(wp + 2*64);
        const float4 w3 = *(const float4*)(wp + 3*64);
        const float4 w4 = *(const float4*)(wp + 4*64);
        const float4 w5 = *(const float4*)(wp + 5*64);
        const float4 w6 = *(const float4*)(wp + 6*64);
        const float4 w7 = *(const float4*)(wp + 7*64);
        a0 += fB.x*w0.x + fB2.x*w1.x + fB.y*w2.x + fB2.y*w3.x
            + fB.z*w4.x + fB2.z*w5.x + fB.w*w6.x + fB2.w*w7.x;
        a1 += fB.x*w0.y + fB2.x*w1.y + fB.y*w2.y + fB2.y*w3.y
            + fB.z*w4.y + fB2.z*w5.y + fB.w*w6.y + fB2.w*w7.y;
        a2 += fB.x*w0.z + fB2.x*w1.z + fB.y*w2.z + fB2.y*w3.z
            + fB.z*w4.z + fB2.z*w5.z + fB.w*w6.z + fB2.w*w7.z;
        a3 += fB.x*w0.w + fB2.x*w1.w + fB.y*w2.w + fB2.y*w3.w
            + fB.z*w4.w + fB2.z*w5.w + fB.w*w6.w + fB2.w*w7.w;
    }
    const float4 bb = *(const float4*)&b1[4 * tx];
    float4 h;
    h.x = a0 + bb.x; h.y = a1 + bb.y; h.z = a2 + bb.z; h.w = a3 + bb.w;
    h.x = h.x / (1.f + __expf(-h.x)); h.y = h.y / (1.f + __expf(-h.y));
    h.z = h.z / (1.f + __expf(-h.z)); h.w = h.w / (1.f + __expf(-h.w));
    *(float4*)&h1s[ty][4 * tx] = h;
    __syncthreads();
    #pragma unroll
    for (int it = tid; it < 16 * 32; it += 256) {
        const int nl = it >> 5, oo = it & 31;
        float g = b2[oo];
        #pragma unroll 8
        for (int k = 0; k < 64; k++) g += h1s[nl][k] * W2[k*32 + oo];
        h2s[nl][oo] = g / (1.f + __expf(-g));
    }
    __syncthreads();
    if (tid < 16) {
        float a3f = b3[0];
        #pragma unroll
        for (int k = 0; k < 32; k++) a3f += h2s[tid][k] * W3[k];
        atomicAdd(out + batch[nb + tid], a3f);
    }
}

extern "C" void kernel_launch(void* const* d_in, const int* in_sizes, int n_in,
                              void* d_out, int out_size, void* d_ws, size_t ws_size,
                              hipStream_t stream)
{
    const float* pos    = (const float*)d_in[0];
    const int*   ntype  = (const int*)  d_in[1];
    const int*   src    = (const int*)  d_in[2];
    const int*   dst    = (const int*)  d_in[3];
    const float* shifts = (const float*)d_in[4];
    const int*   batch  = (const int*)  d_in[5];
    const float* Wemb   = (const float*)d_in[6];
    const float* freqs  = (const float*)d_in[7];
    const float* W_rt   = (const float*)d_in[8];
    const float* W_mem  = (const float*)d_in[9];
    const float* W_Ar   = (const float*)d_in[10];
    const float* W_chi  = (const float*)d_in[11];
    const float* W1     = (const float*)d_in[12];
    const float* b1     = (const float*)d_in[13];
    const float* W2     = (const float*)d_in[14];
    const float* b2     = (const float*)d_in[15];
    const float* W3     = (const float*)d_in[16];
    const float* b3     = (const float*)d_in[17];

    float* ws   = (float*)d_ws;
    float* A    = ws;                        // [NN,1080]
    float* Bf   = A   + (size_t)NN * 1080;   // [NN,324]
    float* B2f  = Bf  + (size_t)NN * 324;    // [NN,324]
    float* chi  = B2f + (size_t)NN * 324;    // [NN,9]
    int*   indeg  = (int*)(chi + (size_t)NN * 9);
    int*   offs   = indeg  + 10240;
    int*   cursor = offs   + 10240;
    int*   elist  = cursor + 10240;          // [NE]

    hipMemsetAsync(indeg,  0, 10240 * sizeof(int), stream);
    hipMemsetAsync(cursor, 0, 10240 * sizeof(int), stream);
    hipMemsetAsync(d_out,  0, (size_t)out_size * sizeof(float), stream);

    k_hist<<<(NE + 255)/256, 256, 0, stream>>>(pos, src, dst, shifts, indeg);
    k_scan<<<1, 256, 0, stream>>>(indeg, offs);
    k_fill<<<(NE + 255)/256, 256, 0, stream>>>(pos, src, dst, shifts, offs,
                                               cursor, elist);
    k_node1<<<NN, 64, 0, stream>>>(pos, ntype, src, shifts, Wemb, freqs, W_rt,
                                   offs, indeg, elist, A, Bf);
    k_chi<<<(NN*9 + 255)/256, 256, 0, stream>>>(Bf, W_chi, chi);
    k_node2<<<NN, 64, 0, stream>>>(pos, ntype, src, shifts, Wemb, freqs, W_rt,
                                   W_Ar, W_mem, offs, indeg, elist, chi, A, B2f);
    k_mlp<<<(NN + 15)/16, 256, 0, stream>>>(Bf, B2f, W1, b1, W2, b2, W3, b3,
                                            batch, (float*)d_out);
}

// Round 5
// 420.073 us; speedup vs baseline: 1.3243x; 1.1330x over previous
//
#include <hip/hip_runtime.h>
#include <hip/hip_bf16.h>
#include <math.h>

#define NE 80000
#define NN 10000
#define NG 16
#define MP_NORM 0.31622776601683794f   // 1/sqrt(10)
#define RBF_NORM 0.60302268915552724f  // sqrt(2/5.5)

// monomial tables: index -> (lx,ly,lz), l
__constant__ int c_mx[20] = {0, 1,0,0, 2,1,1,0,0,0, 3,2,2,1,1,1,0,0,0,0};
__constant__ int c_my[20] = {0, 0,1,0, 0,1,0,2,1,0, 0,1,0,2,1,0,3,2,1,0};
__constant__ int c_mz[20] = {0, 0,0,1, 0,0,1,0,1,2, 0,0,1,0,1,2,0,1,2,3};

__device__ __forceinline__ int l_of_a(int a) {
    return (a >= 10) ? 3 : ((a >= 4) ? 2 : ((a >= 1) ? 1 : 0));
}

// symmetrize one node's 1080-vector (in LDS) -> 324 outputs (global row)
__device__ __forceinline__ void symm_from_lds(const float* Als, float* brow,
                                              int lane) {
    if (lane >= 54) return;
    const int s2 = lane / 9, c = lane - s2 * 9;
    const float* a = Als + s2 * 180 + c;
    float v[20];
    #pragma unroll
    for (int i = 0; i < 20; i++) v[i] = a[i * 9];
    const float o0 = v[0];
    const float o1 = v[1]*v[1] + v[2]*v[2] + v[3]*v[3];
    const float o2 = v[4]*v[4] + 2.f*v[5]*v[5] + 2.f*v[6]*v[6]
                   + v[7]*v[7] + 2.f*v[8]*v[8] + v[9]*v[9];
    const float o3 = v[10]*v[10] + 3.f*v[11]*v[11] + 3.f*v[12]*v[12]
                   + 3.f*v[13]*v[13] + 6.f*v[14]*v[14] + 3.f*v[15]*v[15]
                   + v[16]*v[16] + 3.f*v[17]*v[17] + 3.f*v[18]*v[18] + v[19]*v[19];
    const float o4 = v[1]*v[1]*v[4] + 2.f*v[1]*v[2]*v[5] + 2.f*v[1]*v[3]*v[6]
                   + 2.f*v[2]*v[1]*v[5] + v[2]*v[2]*v[7] + 2.f*v[2]*v[3]*v[8]
                   + 2.f*v[3]*v[1]*v[6] + 2.f*v[3]*v[2]*v[8] + v[3]*v[3]*v[9];
    const float o5 =
        v[1]*(v[4]*v[10] + 3.f*v[5]*v[11] + 3.f*v[6]*v[12] + 3.f*v[7]*v[13]
              + 6.f*v[8]*v[14] + 3.f*v[9]*v[15])
      + v[2]*(3.f*v[4]*v[11] + 3.f*v[5]*v[13] + 6.f*v[6]*v[14] + v[7]*v[16]
              + 3.f*v[8]*v[17] + 3.f*v[9]*v[18])
      + v[3]*(3.f*v[4]*v[12] + 6.f*v[5]*v[14] + 3.f*v[6]*v[15] + 3.f*v[7]*v[17]
              + 3.f*v[8]*v[18] + v[9]*v[19]);
    float* b = brow + s2 * 54 + c;
    b[0]  = o0;
    b[9]  = o1;
    b[18] = o2;
    b[27] = o3;
    b[36] = o4;
    b[45] = o5;
}

// ---------------------------------------------------------------------------
// CSR build: histogram of dst over fc-active edges, scan, fill.
// ---------------------------------------------------------------------------
__global__ __launch_bounds__(256) void k_hist(
    const float* __restrict__ pos, const int* __restrict__ src,
    const int* __restrict__ dst, const float* __restrict__ shifts,
    int* __restrict__ indeg)
{
    const int e = blockIdx.x * 256 + threadIdx.x;
    if (e >= NE) return;
    const int sn = src[e], dn = dst[e];
    const float vx = pos[3*dn+0] - pos[3*sn+0] + shifts[3*e+0];
    const float vy = pos[3*dn+1] - pos[3*sn+1] + shifts[3*e+1];
    const float vz = pos[3*dn+2] - pos[3*sn+2] + shifts[3*e+2];
    const float r = sqrtf(vx*vx + vy*vy + vz*vz) + 1e-9f;
    if (r * (1.0f / 5.5f) < 1.0f) atomicAdd(&indeg[dn], 1);
}

__global__ __launch_bounds__(256) void k_scan(const int* __restrict__ indeg,
                                              int* __restrict__ offs)
{
    __shared__ int part[256];
    const int t = threadIdx.x;
    int s = 0;
    for (int i = t * 40; i < t * 40 + 40; i++)
        if (i < NN) s += indeg[i];
    part[t] = s;
    __syncthreads();
    if (t == 0) {
        int run = 0;
        for (int i = 0; i < 256; i++) { int v = part[i]; part[i] = run; run += v; }
    }
    __syncthreads();
    int run = part[t];
    for (int i = t * 40; i < t * 40 + 40; i++) {
        if (i < NN) { offs[i] = run; run += indeg[i]; }
    }
}

__global__ __launch_bounds__(256) void k_fill(
    const float* __restrict__ pos, const int* __restrict__ src,
    const int* __restrict__ dst, const float* __restrict__ shifts,
    const int* __restrict__ offs, int* __restrict__ cursor,
    int* __restrict__ elist)
{
    const int e = blockIdx.x * 256 + threadIdx.x;
    if (e >= NE) return;
    const int sn = src[e], dn = dst[e];
    const float vx = pos[3*dn+0] - pos[3*sn+0] + shifts[3*e+0];
    const float vy = pos[3*dn+1] - pos[3*sn+1] + shifts[3*e+1];
    const float vz = pos[3*dn+2] - pos[3*sn+2] + shifts[3*e+2];
    const float r = sqrtf(vx*vx + vy*vy + vz*vz) + 1e-9f;
    if (r * (1.0f / 5.5f) < 1.0f) {
        const int p = offs[dn] + atomicAdd(&cursor[dn], 1);
        elist[p] = e;
    }
}

// ---------------------------------------------------------------------------
// Pass 1, gather form: one wave per node, one-edge-ahead prefetch of
// pos/shifts/ntype. Accumulate A[n] in registers, symmetrize inline -> B.
// ---------------------------------------------------------------------------
__global__ __launch_bounds__(64) void k_node1(
    const float* __restrict__ pos, const int* __restrict__ ntype,
    const int* __restrict__ srcArr, const float* __restrict__ shifts,
    const float* __restrict__ Wemb, const float* __restrict__ freqs,
    const float* __restrict__ W_rt, const int* __restrict__ offs,
    const int* __restrict__ indeg, const int* __restrict__ elist,
    float* __restrict__ A, float* __restrict__ Bf)
{
    __shared__ float eS[80];     // ang[0..19], code[20..28], radt[29..52]
    __shared__ float Als[1080];
    const int n = blockIdx.x, lane = threadIdx.x;
    int ridx[17], aidx[17], cidx[17];
    float acc[17];
    #pragma unroll
    for (int k = 0; k < 17; k++) {
        acc[k] = 0.f;
        const int i = lane + 64 * k;
        const int ii = (i < 1080) ? i : 0;
        const int s2 = ii / 180, rem = ii - s2 * 180;
        const int a = rem / 9, c = rem - a * 9;
        ridx[k] = 29 + l_of_a(a) * 6 + s2; aidx[k] = a; cidx[k] = 20 + c;
    }
    const float px = pos[3*n], py = pos[3*n+1], pz = pos[3*n+2];
    const float ed0 = Wemb[3*ntype[n]], ed1 = Wemb[3*ntype[n]+1],
                ed2 = Wemb[3*ntype[n]+2];
    float fr[6];
    #pragma unroll
    for (int q = 0; q < 6; q++) fr[q] = freqs[q];
    float wrt[6];
    if (lane >= 32 && lane < 56) {
        const int j = lane - 32, l = j / 6, s2 = j % 6;
        #pragma unroll
        for (int q = 0; q < 6; q++) wrt[q] = W_rt[(l*6 + q)*6 + s2];
    }
    const int e0 = offs[n], cnt = indeg[n];
    int e_n = 0, sn_n = 0, tn_n = 0;
    float pnx = 0, pny = 0, pnz = 0, snx = 0, sny = 0, snz = 0;
    if (cnt > 0) {
        e_n = elist[e0]; sn_n = srcArr[e_n]; tn_n = ntype[sn_n];
        pnx = pos[3*sn_n]; pny = pos[3*sn_n+1]; pnz = pos[3*sn_n+2];
        snx = shifts[3*e_n]; sny = shifts[3*e_n+1]; snz = shifts[3*e_n+2];
    }
    for (int t = 0; t < cnt; t++) {
        const int tn = tn_n;
        const float vx = px - pnx + snx;
        const float vy = py - pny + sny;
        const float vz = pz - pnz + snz;
        if (t + 1 < cnt) {
            e_n = elist[e0 + t + 1]; sn_n = srcArr[e_n]; tn_n = ntype[sn_n];
            pnx = pos[3*sn_n]; pny = pos[3*sn_n+1]; pnz = pos[3*sn_n+2];
            snx = shifts[3*e_n]; sny = shifts[3*e_n+1]; snz = shifts[3*e_n+2];
        }
        const float r = sqrtf(vx*vx + vy*vy + vz*vz) + 1e-9f;
        const float u = r * (1.0f / 5.5f);
        const float u2 = u*u, u3 = u2*u, u6 = u3*u3;
        const float fcv = 1.0f - 28.0f*u6 + 48.0f*u6*u - 21.0f*u6*u2;
        const float inv = 1.0f / r;
        float rb[6];
        #pragma unroll
        for (int q = 0; q < 6; q++)
            rb[q] = RBF_NORM * __sinf(r * fr[q]) * inv * fcv;
        if (lane < 20) {
            const float ux = vx*inv, uy = vy*inv, uz = vz*inv;
            const int lx = c_mx[lane], ly = c_my[lane], lz = c_mz[lane];
            float v = 1.f;
            for (int i = 0; i < lx; i++) v *= ux;
            for (int i = 0; i < ly; i++) v *= uy;
            for (int i = 0; i < lz; i++) v *= uz;
            eS[lane] = v;
        } else if (lane < 29) {
            const int c = lane - 20, m = c % 3;
            const float ed = (m == 0) ? ed0 : ((m == 1) ? ed1 : ed2);
            eS[lane] = Wemb[3*tn + c/3] * ed;
        } else if (lane >= 32 && lane < 56) {
            float s = 0.f;
            #pragma unroll
            for (int q = 0; q < 6; q++) s += rb[q] * wrt[q];
            eS[lane - 3] = s;
        }
        __syncthreads();
        #pragma unroll
        for (int k = 0; k < 17; k++)
            acc[k] += eS[ridx[k]] * eS[aidx[k]] * eS[cidx[k]];
        __syncthreads();
    }
    #pragma unroll
    for (int k = 0; k < 17; k++) {
        const int i = lane + 64 * k;
        if (i < 1080) { A[(long)n*1080 + i] = acc[k]; Als[i] = acc[k]; }
    }
    __syncthreads();
    symm_from_lds(Als, Bf + (long)n * 324, lane);
}

// chi[n,c'] = B[n,:] . W_chi[:,c']
__global__ __launch_bounds__(256) void k_chi(const float* __restrict__ Bf,
                                             const float* __restrict__ W_chi,
                                             float* __restrict__ chi)
{
    const int t = blockIdx.x * 256 + threadIdx.x;
    if (t >= NN * 9) return;
    const int cp = t % 9, n = t / 9;
    const float* b = Bf + (long)n * 324;
    float s = 0.f;
    #pragma unroll 4
    for (int j = 0; j < 324; j += 4) {
        const float4 bv = *(const float4*)(b + j);
        s += bv.x * W_chi[(j+0)*9 + cp] + bv.y * W_chi[(j+1)*9 + cp]
           + bv.z * W_chi[(j+2)*9 + cp] + bv.w * W_chi[(j+3)*9 + cp];
    }
    chi[t] = s;
}

// ---------------------------------------------------------------------------
// Pass 2, gather form with one-edge-ahead prefetch incl. A[src] row and chi.
// ---------------------------------------------------------------------------
__global__ __launch_bounds__(64) void k_node2(
    const float* __restrict__ pos, const int* __restrict__ ntype,
    const int* __restrict__ srcArr, const float* __restrict__ shifts,
    const float* __restrict__ Wemb, const float* __restrict__ freqs,
    const float* __restrict__ W_rt, const float* __restrict__ W_Ar,
    const float* __restrict__ W_mem, const int* __restrict__ offs,
    const int* __restrict__ indeg, const int* __restrict__ elist,
    const float* __restrict__ chi, const float* __restrict__ A,
    float* __restrict__ B2f)
{
    __shared__ float eS[80];     // ang, codechi[20..28], radtB[29..52], radtA[53..76]
    __shared__ float Als[1080];
    __shared__ float Qls[1080];
    __shared__ float Wm[144];
    const int n = blockIdx.x, lane = threadIdx.x;
    #pragma unroll
    for (int k = 0; k < 17; k++) {
        const int i = lane + 64 * k;
        if (i < 1080) Als[i] = A[(long)n*1080 + i];
    }
    Wm[lane] = W_mem[lane];
    Wm[lane + 64] = W_mem[lane + 64];
    if (lane < 16) Wm[lane + 128] = W_mem[lane + 128];
    int ridx[17], aidx[17], cidx[17];
    float acc[17];
    #pragma unroll
    for (int k = 0; k < 17; k++) {
        acc[k] = 0.f;
        const int i = lane + 64 * k;
        const int ii = (i < 1080) ? i : 0;
        const int s2 = ii / 180, rem = ii - s2 * 180;
        const int a = rem / 9, c = rem - a * 9;
        ridx[k] = 29 + l_of_a(a) * 6 + s2; aidx[k] = a; cidx[k] = 20 + c;
    }
    const float px = pos[3*n], py = pos[3*n+1], pz = pos[3*n+2];
    const float ed0 = Wemb[3*ntype[n]], ed1 = Wemb[3*ntype[n]+1],
                ed2 = Wemb[3*ntype[n]+2];
    float fr[6];
    #pragma unroll
    for (int q = 0; q < 6; q++) fr[q] = freqs[q];
    float wrtB[6], wrtA[6];
    if (lane >= 32 && lane < 56) {
        const int j = lane - 32, l = j / 6, s2 = j % 6;
        #pragma unroll
        for (int q = 0; q < 6; q++) {
            wrtB[q] = W_rt[(l*6 + q)*6 + s2];
            wrtA[q] = W_Ar[(l*6 + q)*6 + s2];
        }
    }
    __syncthreads();
    const int e0 = offs[n], cnt = indeg[n];
    int e_n = 0, sn_n = 0, tn_n = 0;
    float pnx = 0, pny = 0, pnz = 0, snx = 0, sny = 0, snz = 0, chin = 0.f;
    float an[17];
    #pragma unroll
    for (int k = 0; k < 17; k++) an[k] = 0.f;
    if (cnt > 0) {
        e_n = elist[e0]; sn_n = srcArr[e_n]; tn_n = ntype[sn_n];
        pnx = pos[3*sn_n]; pny = pos[3*sn_n+1]; pnz = pos[3*sn_n+2];
        snx = shifts[3*e_n]; sny = shifts[3*e_n+1]; snz = shifts[3*e_n+2];
        if (lane >= 20 && lane < 29) chin = chi[sn_n*9 + (lane - 20)];
        const float* ar = A + (long)sn_n * 1080;
        #pragma unroll
        for (int k = 0; k < 17; k++) {
            const int i = lane + 64 * k;
            if (i < 1080) an[k] = ar[i];
        }
    }
    for (int t = 0; t < cnt; t++) {
        const int tn = tn_n;
        const float chiv = chin;
        const float vx = px - pnx + snx;
        const float vy = py - pny + sny;
        const float vz = pz - pnz + snz;
        float av[17];
        #pragma unroll
        for (int k = 0; k < 17; k++) av[k] = an[k];
        if (t + 1 < cnt) {
            e_n = elist[e0 + t + 1]; sn_n = srcArr[e_n]; tn_n = ntype[sn_n];
            pnx = pos[3*sn_n]; pny = pos[3*sn_n+1]; pnz = pos[3*sn_n+2];
            snx = shifts[3*e_n]; sny = shifts[3*e_n+1]; snz = shifts[3*e_n+2];
            if (lane >= 20 && lane < 29) chin = chi[sn_n*9 + (lane - 20)];
            const float* ar = A + (long)sn_n * 1080;
            #pragma unroll
            for (int k = 0; k < 17; k++) {
                const int i = lane + 64 * k;
                if (i < 1080) an[k] = ar[i];
            }
        }
        const float r = sqrtf(vx*vx + vy*vy + vz*vz) + 1e-9f;
        const float u = r * (1.0f / 5.5f);
        const float u2 = u*u, u3 = u2*u, u6 = u3*u3;
        const float fcv = 1.0f - 28.0f*u6 + 48.0f*u6*u - 21.0f*u6*u2;
        const float inv = 1.0f / r;
        float rb[6];
        #pragma unroll
        for (int q = 0; q < 6; q++)
            rb[q] = RBF_NORM * __sinf(r * fr[q]) * inv * fcv;
        if (lane < 20) {
            const float ux = vx*inv, uy = vy*inv, uz = vz*inv;
            const int lx = c_mx[lane], ly = c_my[lane], lz = c_mz[lane];
            float v = 1.f;
            for (int i = 0; i < lx; i++) v *= ux;
            for (int i = 0; i < ly; i++) v *= uy;
            for (int i = 0; i < lz; i++) v *= uz;
            eS[lane] = v;
        } else if (lane < 29) {
            const int c = lane - 20, m = c % 3;
            const float ed = (m == 0) ? ed0 : ((m == 1) ? ed1 : ed2);
            eS[lane] = Wemb[3*tn + c/3] * ed * chiv;
        } else if (lane >= 32 && lane < 56) {
            float sB = 0.f, sA = 0.f;
            #pragma unroll
            for (int q = 0; q < 6; q++) { sB += rb[q]*wrtB[q]; sA += rb[q]*wrtA[q]; }
            eS[lane - 3]  = sB;
            eS[lane + 21] = sA;
        }
        __syncthreads();
        #pragma unroll
        for (int k = 0; k < 17; k++) {
            const int i = lane + 64 * k;
            if (i < 1080)
                acc[k] += eS[ridx[k]] * eS[aidx[k]] * eS[cidx[k]]
                        + av[k] * eS[ridx[k] + 24];
        }
        __syncthreads();
    }
    // memory term + MP_NORM -> Qls
    #pragma unroll
    for (int k = 0; k < 17; k++) {
        const int i = lane + 64 * k;
        if (i < 1080) {
            const int l6 = ridx[k] - 29;
            const int l = l6 / 6, s2v = l6 - 6 * l;
            const int rem = aidx[k] * 9 + (cidx[k] - 20);
            float m = 0.f;
            #pragma unroll
            for (int sp = 0; sp < 6; sp++)
                m += Als[sp*180 + rem] * Wm[l*36 + sp*6 + s2v];
            Qls[i] = acc[k] * MP_NORM + m;
        }
    }
    __syncthreads();
    symm_from_lds(Qls, B2f + (long)n * 324, lane);
}

// ---------------------------------------------------------------------------
// MLP readout v5: 64 nodes/block, lane = node. Wave w owns outputs
// [16w,16w+16). feats chunk (108 cols) staged in LDS As[108][65]; W1 rows
// are wave-uniform (scalar loads). Inner body: 1 ds_read + 16 FMA.
// ---------------------------------------------------------------------------
__global__ __launch_bounds__(256) void k_mlp(
    const float* __restrict__ Bf, const float* __restrict__ B2f,
    const float* __restrict__ W1, const float* __restrict__ b1,
    const float* __restrict__ W2, const float* __restrict__ b2,
    const float* __restrict__ W3, const float* __restrict__ b3,
    const int* __restrict__ batch, float* __restrict__ out)
{
    __shared__ float As[108][65];
    __shared__ float h1T[64][65];
    __shared__ float red[4][64];
    const int tid = threadIdx.x;
    const int lane = tid & 63;
    const int wq = __builtin_amdgcn_readfirstlane(tid >> 6);
    const int nb = blockIdx.x * 64;
    const int nvalid = NN - nb < 64 ? NN - nb : 64;
    float acc[16];
    #pragma unroll
    for (int i = 0; i < 16; i++) acc[i] = 0.f;
    // 6 chunks of 108 cols: 0..2 from Bf, 3..5 from B2f (K-order permuted)
    for (int ch = 0; ch < 6; ch++) {
        const int half = (ch >= 3) ? 1 : 0;
        const int k0 = (ch - 3 * half) * 108;
        const float* srcM = half ? B2f : Bf;
        // stage: thread (m = tid>>2, part = (tid&3)*27) loads 27 contiguous
        const int m = tid >> 2, part = (tid & 3) * 27;
        float pf[27];
        if (m < nvalid) {
            const float* g = srcM + (long)(nb + m) * 324 + k0 + part;
            #pragma unroll
            for (int i = 0; i < 27; i++) pf[i] = g[i];
        } else {
            #pragma unroll
            for (int i = 0; i < 27; i++) pf[i] = 0.f;
        }
        __syncthreads();   // all waves done reading As of previous chunk
        #pragma unroll
        for (int i = 0; i < 27; i++) As[part + i][m] = pf[i];
        __syncthreads();
        const int rowbase = 2 * k0 + half;
        #pragma unroll 4
        for (int kk = 0; kk < 108; kk++) {
            const float a = As[kk][lane];
            const float* wrow = W1 + (size_t)(rowbase + 2 * kk) * 64 + 16 * wq;
            #pragma unroll
            for (int i = 0; i < 16; i++)
                acc[i] = fmaf(a, wrow[i], acc[i]);
        }
    }
    // layer-1 activation -> h1T[o][node]
    const float* b1p = b1 + 16 * wq;
    #pragma unroll
    for (int i = 0; i < 16; i++) {
        float h = acc[i] + b1p[i];
        h = h / (1.f + __expf(-h));
        h1T[16 * wq + i][lane] = h;
    }
    __syncthreads();
    // layer 2: wave w owns outputs [8w, 8w+8)
    float acc2[8];
    const float* b2p = b2 + 8 * wq;
    #pragma unroll
    for (int j = 0; j < 8; j++) acc2[j] = b2p[j];
    #pragma unroll 4
    for (int k = 0; k < 64; k++) {
        const float h = h1T[k][lane];
        const float* w2row = W2 + k * 32 + 8 * wq;
        #pragma unroll
        for (int j = 0; j < 8; j++)
            acc2[j] = fmaf(h, w2row[j], acc2[j]);
    }
    // layer 3 partial over this wave's 8 outputs
    float part3 = 0.f;
    const float* w3p = W3 + 8 * wq;
    #pragma unroll
    for (int j = 0; j < 8; j++) {
        const float g = acc2[j] / (1.f + __expf(-acc2[j]));
        part3 += g * w3p[j];
    }
    red[wq][lane] = part3;
    __syncthreads();
    if (tid < 64 && tid < nvalid) {
        const float tot = red[0][tid] + red[1][tid] + red[2][tid]
                        + red[3][tid] + b3[0];
        atomicAdd(out + batch[nb + tid], tot);
    }
}

extern "C" void kernel_launch(void* const* d_in, const int* in_sizes, int n_in,
                              void* d_out, int out_size, void* d_ws, size_t ws_size,
                              hipStream_t stream)
{
    const float* pos    = (const float*)d_in[0];
    const int*   ntype  = (const int*)  d_in[1];
    const int*   src    = (const int*)  d_in[2];
    const int*   dst    = (const int*)  d_in[3];
    const float* shifts = (const float*)d_in[4];
    const int*   batch  = (const int*)  d_in[5];
    const float* Wemb   = (const float*)d_in[6];
    const float* freqs  = (const float*)d_in[7];
    const float* W_rt   = (const float*)d_in[8];
    const float* W_mem  = (const float*)d_in[9];
    const float* W_Ar   = (const float*)d_in[10];
    const float* W_chi  = (const float*)d_in[11];
    const float* W1     = (const float*)d_in[12];
    const float* b1     = (const float*)d_in[13];
    const float* W2     = (const float*)d_in[14];
    const float* b2     = (const float*)d_in[15];
    const float* W3     = (const float*)d_in[16];
    const float* b3     = (const float*)d_in[17];

    float* ws   = (float*)d_ws;
    float* A    = ws;                        // [NN,1080]
    float* Bf   = A   + (size_t)NN * 1080;   // [NN,324]
    float* B2f  = Bf  + (size_t)NN * 324;    // [NN,324]
    float* chi  = B2f + (size_t)NN * 324;    // [NN,9]
    int*   indeg  = (int*)(chi + (size_t)NN * 9);
    int*   offs   = indeg  + 10240;
    int*   cursor = offs   + 10240;
    int*   elist  = cursor + 10240;          // [NE]

    hipMemsetAsync(indeg,  0, 10240 * sizeof(int), stream);
    hipMemsetAsync(cursor, 0, 10240 * sizeof(int), stream);
    hipMemsetAsync(d_out,  0, (size_t)out_size * sizeof(float), stream);

    k_hist<<<(NE + 255)/256, 256, 0, stream>>>(pos, src, dst, shifts, indeg);
    k_scan<<<1, 256, 0, stream>>>(indeg, offs);
    k_fill<<<(NE + 255)/256, 256, 0, stream>>>(pos, src, dst, shifts, offs,
                                               cursor, elist);
    k_node1<<<NN, 64, 0, stream>>>(pos, ntype, src, shifts, Wemb, freqs, W_rt,
                                   offs, indeg, elist, A, Bf);
    k_chi<<<(NN*9 + 255)/256, 256, 0, stream>>>(Bf, W_chi, chi);
    k_node2<<<NN, 64, 0, stream>>>(pos, ntype, src, shifts, Wemb, freqs, W_rt,
                                   W_Ar, W_mem, offs, indeg, elist, chi, A, B2f);
    k_mlp<<<(NN + 63)/64, 256, 0, stream>>>(Bf, B2f, W1, b1, W2, b2, W3, b3,
                                            batch, (float*)d_out);
}

// Round 6
// 413.347 us; speedup vs baseline: 1.3458x; 1.0163x over previous
//
#include <hip/hip_runtime.h>
#include <hip/hip_bf16.h>
#include <math.h>

#define NE 80000
#define NN 10000
#define NG 16
#define MP_NORM 0.31622776601683794f   // 1/sqrt(10)
#define RBF_NORM 0.60302268915552724f  // sqrt(2/5.5)

// monomial tables: index -> (lx,ly,lz), l
__constant__ int c_mx[20] = {0, 1,0,0, 2,1,1,0,0,0, 3,2,2,1,1,1,0,0,0,0};
__constant__ int c_my[20] = {0, 0,1,0, 0,1,0,2,1,0, 0,1,0,2,1,0,3,2,1,0};
__constant__ int c_mz[20] = {0, 0,0,1, 0,0,1,0,1,2, 0,0,1,0,1,2,0,1,2,3};

__device__ __forceinline__ int l_of_a(int a) {
    return (a >= 10) ? 3 : ((a >= 4) ? 2 : ((a >= 1) ? 1 : 0));
}

// symmetrize one node's 1080-vector (in LDS) -> 324 outputs (global row)
__device__ __forceinline__ void symm_from_lds(const float* Als, float* brow,
                                              int lane) {
    if (lane >= 54) return;
    const int s2 = lane / 9, c = lane - s2 * 9;
    const float* a = Als + s2 * 180 + c;
    float v[20];
    #pragma unroll
    for (int i = 0; i < 20; i++) v[i] = a[i * 9];
    const float o0 = v[0];
    const float o1 = v[1]*v[1] + v[2]*v[2] + v[3]*v[3];
    const float o2 = v[4]*v[4] + 2.f*v[5]*v[5] + 2.f*v[6]*v[6]
                   + v[7]*v[7] + 2.f*v[8]*v[8] + v[9]*v[9];
    const float o3 = v[10]*v[10] + 3.f*v[11]*v[11] + 3.f*v[12]*v[12]
                   + 3.f*v[13]*v[13] + 6.f*v[14]*v[14] + 3.f*v[15]*v[15]
                   + v[16]*v[16] + 3.f*v[17]*v[17] + 3.f*v[18]*v[18] + v[19]*v[19];
    const float o4 = v[1]*v[1]*v[4] + 2.f*v[1]*v[2]*v[5] + 2.f*v[1]*v[3]*v[6]
                   + 2.f*v[2]*v[1]*v[5] + v[2]*v[2]*v[7] + 2.f*v[2]*v[3]*v[8]
                   + 2.f*v[3]*v[1]*v[6] + 2.f*v[3]*v[2]*v[8] + v[3]*v[3]*v[9];
    const float o5 =
        v[1]*(v[4]*v[10] + 3.f*v[5]*v[11] + 3.f*v[6]*v[12] + 3.f*v[7]*v[13]
              + 6.f*v[8]*v[14] + 3.f*v[9]*v[15])
      + v[2]*(3.f*v[4]*v[11] + 3.f*v[5]*v[13] + 6.f*v[6]*v[14] + v[7]*v[16]
              + 3.f*v[8]*v[17] + 3.f*v[9]*v[18])
      + v[3]*(3.f*v[4]*v[12] + 6.f*v[5]*v[14] + 3.f*v[6]*v[15] + 3.f*v[7]*v[17]
              + 3.f*v[8]*v[18] + v[9]*v[19]);
    float* b = brow + s2 * 54 + c;
    b[0]  = o0;
    b[9]  = o1;
    b[18] = o2;
    b[27] = o3;
    b[36] = o4;
    b[45] = o5;
}

// ---------------------------------------------------------------------------
// CSR build: histogram of dst over fc-active edges, scan, fill.
// ---------------------------------------------------------------------------
__global__ __launch_bounds__(256) void k_hist(
    const float* __restrict__ pos, const int* __restrict__ src,
    const int* __restrict__ dst, const float* __restrict__ shifts,
    int* __restrict__ indeg)
{
    const int e = blockIdx.x * 256 + threadIdx.x;
    if (e >= NE) return;
    const int sn = src[e], dn = dst[e];
    const float vx = pos[3*dn+0] - pos[3*sn+0] + shifts[3*e+0];
    const float vy = pos[3*dn+1] - pos[3*sn+1] + shifts[3*e+1];
    const float vz = pos[3*dn+2] - pos[3*sn+2] + shifts[3*e+2];
    const float r = sqrtf(vx*vx + vy*vy + vz*vz) + 1e-9f;
    if (r * (1.0f / 5.5f) < 1.0f) atomicAdd(&indeg[dn], 1);
}

__global__ __launch_bounds__(256) void k_scan(const int* __restrict__ indeg,
                                              int* __restrict__ offs)
{
    __shared__ int part[256];
    const int t = threadIdx.x;
    int s = 0;
    for (int i = t * 40; i < t * 40 + 40; i++)
        if (i < NN) s += indeg[i];
    part[t] = s;
    __syncthreads();
    if (t == 0) {
        int run = 0;
        for (int i = 0; i < 256; i++) { int v = part[i]; part[i] = run; run += v; }
    }
    __syncthreads();
    int run = part[t];
    for (int i = t * 40; i < t * 40 + 40; i++) {
        if (i < NN) { offs[i] = run; run += indeg[i]; }
    }
}

__global__ __launch_bounds__(256) void k_fill(
    const float* __restrict__ pos, const int* __restrict__ src,
    const int* __restrict__ dst, const float* __restrict__ shifts,
    const int* __restrict__ offs, int* __restrict__ cursor,
    int* __restrict__ elist)
{
    const int e = blockIdx.x * 256 + threadIdx.x;
    if (e >= NE) return;
    const int sn = src[e], dn = dst[e];
    const float vx = pos[3*dn+0] - pos[3*sn+0] + shifts[3*e+0];
    const float vy = pos[3*dn+1] - pos[3*sn+1] + shifts[3*e+1];
    const float vz = pos[3*dn+2] - pos[3*sn+2] + shifts[3*e+2];
    const float r = sqrtf(vx*vx + vy*vy + vz*vz) + 1e-9f;
    if (r * (1.0f / 5.5f) < 1.0f) {
        const int p = offs[dn] + atomicAdd(&cursor[dn], 1);
        elist[p] = e;
    }
}

// ---------------------------------------------------------------------------
// Pass 1, gather form: one wave per node, one-edge-ahead prefetch of
// pos/shifts/ntype. Accumulate A[n] in registers, symmetrize inline -> B.
// ---------------------------------------------------------------------------
__global__ __launch_bounds__(64) void k_node1(
    const float* __restrict__ pos, const int* __restrict__ ntype,
    const int* __restrict__ srcArr, const float* __restrict__ shifts,
    const float* __restrict__ Wemb, const float* __restrict__ freqs,
    const float* __restrict__ W_rt, const int* __restrict__ offs,
    const int* __restrict__ indeg, const int* __restrict__ elist,
    float* __restrict__ A, float* __restrict__ Bf)
{
    __shared__ float eS[80];     // ang[0..19], code[20..28], radt[29..52]
    __shared__ float Als[1080];
    const int n = blockIdx.x, lane = threadIdx.x;
    int ridx[17], aidx[17], cidx[17];
    float acc[17];
    #pragma unroll
    for (int k = 0; k < 17; k++) {
        acc[k] = 0.f;
        const int i = lane + 64 * k;
        const int ii = (i < 1080) ? i : 0;
        const int s2 = ii / 180, rem = ii - s2 * 180;
        const int a = rem / 9, c = rem - a * 9;
        ridx[k] = 29 + l_of_a(a) * 6 + s2; aidx[k] = a; cidx[k] = 20 + c;
    }
    const float px = pos[3*n], py = pos[3*n+1], pz = pos[3*n+2];
    const float ed0 = Wemb[3*ntype[n]], ed1 = Wemb[3*ntype[n]+1],
                ed2 = Wemb[3*ntype[n]+2];
    float fr[6];
    #pragma unroll
    for (int q = 0; q < 6; q++) fr[q] = freqs[q];
    float wrt[6];
    if (lane >= 32 && lane < 56) {
        const int j = lane - 32, l = j / 6, s2 = j % 6;
        #pragma unroll
        for (int q = 0; q < 6; q++) wrt[q] = W_rt[(l*6 + q)*6 + s2];
    }
    const int e0 = offs[n], cnt = indeg[n];
    int e_n = 0, sn_n = 0, tn_n = 0;
    float pnx = 0, pny = 0, pnz = 0, snx = 0, sny = 0, snz = 0;
    if (cnt > 0) {
        e_n = elist[e0]; sn_n = srcArr[e_n]; tn_n = ntype[sn_n];
        pnx = pos[3*sn_n]; pny = pos[3*sn_n+1]; pnz = pos[3*sn_n+2];
        snx = shifts[3*e_n]; sny = shifts[3*e_n+1]; snz = shifts[3*e_n+2];
    }
    for (int t = 0; t < cnt; t++) {
        const int tn = tn_n;
        const float vx = px - pnx + snx;
        const float vy = py - pny + sny;
        const float vz = pz - pnz + snz;
        if (t + 1 < cnt) {
            e_n = elist[e0 + t + 1]; sn_n = srcArr[e_n]; tn_n = ntype[sn_n];
            pnx = pos[3*sn_n]; pny = pos[3*sn_n+1]; pnz = pos[3*sn_n+2];
            snx = shifts[3*e_n]; sny = shifts[3*e_n+1]; snz = shifts[3*e_n+2];
        }
        const float r = sqrtf(vx*vx + vy*vy + vz*vz) + 1e-9f;
        const float u = r * (1.0f / 5.5f);
        const float u2 = u*u, u3 = u2*u, u6 = u3*u3;
        const float fcv = 1.0f - 28.0f*u6 + 48.0f*u6*u - 21.0f*u6*u2;
        const float inv = 1.0f / r;
        float rb[6];
        #pragma unroll
        for (int q = 0; q < 6; q++)
            rb[q] = RBF_NORM * __sinf(r * fr[q]) * inv * fcv;
        if (lane < 20) {
            const float ux = vx*inv, uy = vy*inv, uz = vz*inv;
            const int lx = c_mx[lane], ly = c_my[lane], lz = c_mz[lane];
            float v = 1.f;
            for (int i = 0; i < lx; i++) v *= ux;
            for (int i = 0; i < ly; i++) v *= uy;
            for (int i = 0; i < lz; i++) v *= uz;
            eS[lane] = v;
        } else if (lane < 29) {
            const int c = lane - 20, m = c % 3;
            const float ed = (m == 0) ? ed0 : ((m == 1) ? ed1 : ed2);
            eS[lane] = Wemb[3*tn + c/3] * ed;
        } else if (lane >= 32 && lane < 56) {
            float s = 0.f;
            #pragma unroll
            for (int q = 0; q < 6; q++) s += rb[q] * wrt[q];
            eS[lane - 3] = s;
        }
        __syncthreads();
        #pragma unroll
        for (int k = 0; k < 17; k++)
            acc[k] += eS[ridx[k]] * eS[aidx[k]] * eS[cidx[k]];
        __syncthreads();
    }
    #pragma unroll
    for (int k = 0; k < 17; k++) {
        const int i = lane + 64 * k;
        if (i < 1080) { A[(long)n*1080 + i] = acc[k]; Als[i] = acc[k]; }
    }
    __syncthreads();
    symm_from_lds(Als, Bf + (long)n * 324, lane);
}

// chi[n,c'] = B[n,:] . W_chi[:,c']
__global__ __launch_bounds__(256) void k_chi(const float* __restrict__ Bf,
                                             const float* __restrict__ W_chi,
                                             float* __restrict__ chi)
{
    const int t = blockIdx.x * 256 + threadIdx.x;
    if (t >= NN * 9) return;
    const int cp = t % 9, n = t / 9;
    const float* b = Bf + (long)n * 324;
    float s = 0.f;
    #pragma unroll 4
    for (int j = 0; j < 324; j += 4) {
        const float4 bv = *(const float4*)(b + j);
        s += bv.x * W_chi[(j+0)*9 + cp] + bv.y * W_chi[(j+1)*9 + cp]
           + bv.z * W_chi[(j+2)*9 + cp] + bv.w * W_chi[(j+3)*9 + cp];
    }
    chi[t] = s;
}

// ---------------------------------------------------------------------------
// Pass 2, gather form with one-edge-ahead prefetch incl. A[src] row and chi.
// ---------------------------------------------------------------------------
__global__ __launch_bounds__(64) void k_node2(
    const float* __restrict__ pos, const int* __restrict__ ntype,
    const int* __restrict__ srcArr, const float* __restrict__ shifts,
    const float* __restrict__ Wemb, const float* __restrict__ freqs,
    const float* __restrict__ W_rt, const float* __restrict__ W_Ar,
    const float* __restrict__ W_mem, const int* __restrict__ offs,
    const int* __restrict__ indeg, const int* __restrict__ elist,
    const float* __restrict__ chi, const float* __restrict__ A,
    float* __restrict__ B2f)
{
    __shared__ float eS[80];     // ang, codechi[20..28], radtB[29..52], radtA[53..76]
    __shared__ float Als[1080];
    __shared__ float Qls[1080];
    __shared__ float Wm[144];
    const int n = blockIdx.x, lane = threadIdx.x;
    #pragma unroll
    for (int k = 0; k < 17; k++) {
        const int i = lane + 64 * k;
        if (i < 1080) Als[i] = A[(long)n*1080 + i];
    }
    Wm[lane] = W_mem[lane];
    Wm[lane + 64] = W_mem[lane + 64];
    if (lane < 16) Wm[lane + 128] = W_mem[lane + 128];
    int ridx[17], aidx[17], cidx[17];
    float acc[17];
    #pragma unroll
    for (int k = 0; k < 17; k++) {
        acc[k] = 0.f;
        const int i = lane + 64 * k;
        const int ii = (i < 1080) ? i : 0;
        const int s2 = ii / 180, rem = ii - s2 * 180;
        const int a = rem / 9, c = rem - a * 9;
        ridx[k] = 29 + l_of_a(a) * 6 + s2; aidx[k] = a; cidx[k] = 20 + c;
    }
    const float px = pos[3*n], py = pos[3*n+1], pz = pos[3*n+2];
    const float ed0 = Wemb[3*ntype[n]], ed1 = Wemb[3*ntype[n]+1],
                ed2 = Wemb[3*ntype[n]+2];
    float fr[6];
    #pragma unroll
    for (int q = 0; q < 6; q++) fr[q] = freqs[q];
    float wrtB[6], wrtA[6];
    if (lane >= 32 && lane < 56) {
        const int j = lane - 32, l = j / 6, s2 = j % 6;
        #pragma unroll
        for (int q = 0; q < 6; q++) {
            wrtB[q] = W_rt[(l*6 + q)*6 + s2];
            wrtA[q] = W_Ar[(l*6 + q)*6 + s2];
        }
    }
    __syncthreads();
    const int e0 = offs[n], cnt = indeg[n];
    int e_n = 0, sn_n = 0, tn_n = 0;
    float pnx = 0, pny = 0, pnz = 0, snx = 0, sny = 0, snz = 0, chin = 0.f;
    float an[17];
    #pragma unroll
    for (int k = 0; k < 17; k++) an[k] = 0.f;
    if (cnt > 0) {
        e_n = elist[e0]; sn_n = srcArr[e_n]; tn_n = ntype[sn_n];
        pnx = pos[3*sn_n]; pny = pos[3*sn_n+1]; pnz = pos[3*sn_n+2];
        snx = shifts[3*e_n]; sny = shifts[3*e_n+1]; snz = shifts[3*e_n+2];
        if (lane >= 20 && lane < 29) chin = chi[sn_n*9 + (lane - 20)];
        const float* ar = A + (long)sn_n * 1080;
        #pragma unroll
        for (int k = 0; k < 17; k++) {
            const int i = lane + 64 * k;
            if (i < 1080) an[k] = ar[i];
        }
    }
    for (int t = 0; t < cnt; t++) {
        const int tn = tn_n;
        const float chiv = chin;
        const float vx = px - pnx + snx;
        const float vy = py - pny + sny;
        const float vz = pz - pnz + snz;
        float av[17];
        #pragma unroll
        for (int k = 0; k < 17; k++) av[k] = an[k];
        if (t + 1 < cnt) {
            e_n = elist[e0 + t + 1]; sn_n = srcArr[e_n]; tn_n = ntype[sn_n];
            pnx = pos[3*sn_n]; pny = pos[3*sn_n+1]; pnz = pos[3*sn_n+2];
            snx = shifts[3*e_n]; sny = shifts[3*e_n+1]; snz = shifts[3*e_n+2];
            if (lane >= 20 && lane < 29) chin = chi[sn_n*9 + (lane - 20)];
            const float* ar = A + (long)sn_n * 1080;
            #pragma unroll
            for (int k = 0; k < 17; k++) {
                const int i = lane + 64 * k;
                if (i < 1080) an[k] = ar[i];
            }
        }
        const float r = sqrtf(vx*vx + vy*vy + vz*vz) + 1e-9f;
        const float u = r * (1.0f / 5.5f);
        const float u2 = u*u, u3 = u2*u, u6 = u3*u3;
        const float fcv = 1.0f - 28.0f*u6 + 48.0f*u6*u - 21.0f*u6*u2;
        const float inv = 1.0f / r;
        float rb[6];
        #pragma unroll
        for (int q = 0; q < 6; q++)
            rb[q] = RBF_NORM * __sinf(r * fr[q]) * inv * fcv;
        if (lane < 20) {
            const float ux = vx*inv, uy = vy*inv, uz = vz*inv;
            const int lx = c_mx[lane], ly = c_my[lane], lz = c_mz[lane];
            float v = 1.f;
            for (int i = 0; i < lx; i++) v *= ux;
            for (int i = 0; i < ly; i++) v *= uy;
            for (int i = 0; i < lz; i++) v *= uz;
            eS[lane] = v;
        } else if (lane < 29) {
            const int c = lane - 20, m = c % 3;
            const float ed = (m == 0) ? ed0 : ((m == 1) ? ed1 : ed2);
            eS[lane] = Wemb[3*tn + c/3] * ed * chiv;
        } else if (lane >= 32 && lane < 56) {
            float sB = 0.f, sA = 0.f;
            #pragma unroll
            for (int q = 0; q < 6; q++) { sB += rb[q]*wrtB[q]; sA += rb[q]*wrtA[q]; }
            eS[lane - 3]  = sB;
            eS[lane + 21] = sA;
        }
        __syncthreads();
        #pragma unroll
        for (int k = 0; k < 17; k++) {
            const int i = lane + 64 * k;
            if (i < 1080)
                acc[k] += eS[ridx[k]] * eS[aidx[k]] * eS[cidx[k]]
                        + av[k] * eS[ridx[k] + 24];
        }
        __syncthreads();
    }
    // memory term + MP_NORM -> Qls
    #pragma unroll
    for (int k = 0; k < 17; k++) {
        const int i = lane + 64 * k;
        if (i < 1080) {
            const int l6 = ridx[k] - 29;
            const int l = l6 / 6, s2v = l6 - 6 * l;
            const int rem = aidx[k] * 9 + (cidx[k] - 20);
            float m = 0.f;
            #pragma unroll
            for (int sp = 0; sp < 6; sp++)
                m += Als[sp*180 + rem] * Wm[l*36 + sp*6 + s2v];
            Qls[i] = acc[k] * MP_NORM + m;
        }
    }
    __syncthreads();
    symm_from_lds(Qls, B2f + (long)n * 324, lane);
}

// ---------------------------------------------------------------------------
// MLP readout v6: 64 nodes/block, lane = output column. ALL operands staged
// in LDS (feats chunk As, W1 chunk Ws, W2^T) -> inner loop is pure LDS+VALU,
// no SMEM/VMEM (avoids lgkmcnt serialization of scalar loads vs ds_read).
// Wave wq owns nodes [16wq,16wq+16); per 4-k body: 4 ds_b32 + 16 ds_b128
// (uniform broadcast) + 64 FMA.
// ---------------------------------------------------------------------------
__global__ __launch_bounds__(256) void k_mlp(
    const float* __restrict__ Bf, const float* __restrict__ B2f,
    const float* __restrict__ W1, const float* __restrict__ b1,
    const float* __restrict__ W2, const float* __restrict__ b2,
    const float* __restrict__ W3, const float* __restrict__ b3,
    const int* __restrict__ batch, float* __restrict__ out)
{
    __shared__ float As[64][112];    // node x K-chunk (108 used, 16B-aligned rows)
    __shared__ float Ws[108][64];    // K-chunk x output
    __shared__ float h1T[64][65];    // output x node
    __shared__ float W2T[32][68];    // output2 x k   (16B-aligned rows)
    __shared__ float red[4][64];
    const int tid = threadIdx.x;
    const int lane = tid & 63;       // layer1: output col; layer2: node
    const int wq = tid >> 6;
    const int nb = blockIdx.x * 64;
    const int nvalid = (NN - nb < 64) ? (NN - nb) : 64;
    // stage W2 transposed once
    for (int idx = tid; idx < 2048; idx += 256) {
        const int k = idx >> 5, o = idx & 31;
        W2T[o][k] = W2[idx];
    }
    float acc[16];
    #pragma unroll
    for (int i = 0; i < 16; i++) acc[i] = 0.f;
    const int ms = tid >> 2, part = (tid & 3) * 27;
    for (int ch = 0; ch < 6; ch++) {
        const int half = (ch >= 3) ? 1 : 0;
        const int k0 = (ch - 3 * half) * 108;
        const float* srcM = half ? B2f : Bf;
        // prefetch to regs (overlaps previous chunk's compute)
        float pf[27];
        if (ms < nvalid) {
            const float* g = srcM + (long)(nb + ms) * 324 + k0 + part;
            #pragma unroll
            for (int i = 0; i < 27; i++) pf[i] = g[i];
        } else {
            #pragma unroll
            for (int i = 0; i < 27; i++) pf[i] = 0.f;
        }
        float wf[27];
        {
            const int rowbase = 2 * k0 + half;
            #pragma unroll
            for (int i = 0; i < 27; i++) {
                const int idx = tid + 256 * i;
                const int kk = idx >> 6, o = idx & 63;
                wf[i] = W1[(size_t)(rowbase + 2 * kk) * 64 + o];
            }
        }
        __syncthreads();   // previous chunk's compute done before overwrite
        #pragma unroll
        for (int i = 0; i < 27; i++) As[ms][part + i] = pf[i];
        #pragma unroll
        for (int i = 0; i < 27; i++) {
            const int idx = tid + 256 * i;
            Ws[idx >> 6][idx & 63] = wf[i];
        }
        __syncthreads();
        #pragma unroll 3
        for (int k4 = 0; k4 < 27; k4++) {
            const float w0 = Ws[4*k4 + 0][lane];
            const float w1v = Ws[4*k4 + 1][lane];
            const float w2v = Ws[4*k4 + 2][lane];
            const float w3v = Ws[4*k4 + 3][lane];
            #pragma unroll
            for (int mm = 0; mm < 16; mm++) {
                const float4 a = *(const float4*)&As[16*wq + mm][4*k4];
                acc[mm] = fmaf(a.x, w0,  acc[mm]);
                acc[mm] = fmaf(a.y, w1v, acc[mm]);
                acc[mm] = fmaf(a.z, w2v, acc[mm]);
                acc[mm] = fmaf(a.w, w3v, acc[mm]);
            }
        }
    }
    // layer-1 activation -> h1T[output][node]
    const float bb = b1[lane];
    #pragma unroll
    for (int mm = 0; mm < 16; mm++) {
        float h = acc[mm] + bb;
        h = h / (1.f + __expf(-h));
        h1T[lane][16*wq + mm] = h;
    }
    __syncthreads();
    // layer 2: lane = node; wave wq owns outputs [8wq, 8wq+8)
    float acc2[8];
    #pragma unroll
    for (int j = 0; j < 8; j++) acc2[j] = b2[8*wq + j];
    #pragma unroll 4
    for (int k4 = 0; k4 < 16; k4++) {
        float hv[4];
        #pragma unroll
        for (int q = 0; q < 4; q++) hv[q] = h1T[4*k4 + q][lane];
        #pragma unroll
        for (int j = 0; j < 8; j++) {
            const float4 wv = *(const float4*)&W2T[8*wq + j][4*k4];
            acc2[j] += hv[0]*wv.x + hv[1]*wv.y + hv[2]*wv.z + hv[3]*wv.w;
        }
    }
    // layer 3 partial over this wave's 8 outputs
    float part3 = 0.f;
    #pragma unroll
    for (int j = 0; j < 8; j++) {
        const float g = acc2[j] / (1.f + __expf(-acc2[j]));
        part3 += g * W3[8*wq + j];
    }
    red[wq][lane] = part3;
    __syncthreads();
    if (tid < nvalid) {
        const float tot = red[0][tid] + red[1][tid] + red[2][tid] + red[3][tid]
                        + b3[0];
        atomicAdd(out + batch[nb + tid], tot);
    }
}

extern "C" void kernel_launch(void* const* d_in, const int* in_sizes, int n_in,
                              void* d_out, int out_size, void* d_ws, size_t ws_size,
                              hipStream_t stream)
{
    const float* pos    = (const float*)d_in[0];
    const int*   ntype  = (const int*)  d_in[1];
    const int*   src    = (const int*)  d_in[2];
    const int*   dst    = (const int*)  d_in[3];
    const float* shifts = (const float*)d_in[4];
    const int*   batch  = (const int*)  d_in[5];
    const float* Wemb   = (const float*)d_in[6];
    const float* freqs  = (const float*)d_in[7];
    const float* W_rt   = (const float*)d_in[8];
    const float* W_mem  = (const float*)d_in[9];
    const float* W_Ar   = (const float*)d_in[10];
    const float* W_chi  = (const float*)d_in[11];
    const float* W1     = (const float*)d_in[12];
    const float* b1     = (const float*)d_in[13];
    const float* W2     = (const float*)d_in[14];
    const float* b2     = (const float*)d_in[15];
    const float* W3     = (const float*)d_in[16];
    const float* b3     = (const float*)d_in[17];

    float* ws   = (float*)d_ws;
    float* A    = ws;                        // [NN,1080]
    float* Bf   = A   + (size_t)NN * 1080;   // [NN,324]
    float* B2f  = Bf  + (size_t)NN * 324;    // [NN,324]
    float* chi  = B2f + (size_t)NN * 324;    // [NN,9]
    int*   indeg  = (int*)(chi + (size_t)NN * 9);
    int*   offs   = indeg  + 10240;
    int*   cursor = offs   + 10240;
    int*   elist  = cursor + 10240;          // [NE]

    hipMemsetAsync(indeg,  0, 10240 * sizeof(int), stream);
    hipMemsetAsync(cursor, 0, 10240 * sizeof(int), stream);
    hipMemsetAsync(d_out,  0, (size_t)out_size * sizeof(float), stream);

    k_hist<<<(NE + 255)/256, 256, 0, stream>>>(pos, src, dst, shifts, indeg);
    k_scan<<<1, 256, 0, stream>>>(indeg, offs);
    k_fill<<<(NE + 255)/256, 256, 0, stream>>>(pos, src, dst, shifts, offs,
                                               cursor, elist);
    k_node1<<<NN, 64, 0, stream>>>(pos, ntype, src, shifts, Wemb, freqs, W_rt,
                                   offs, indeg, elist, A, Bf);
    k_chi<<<(NN*9 + 255)/256, 256, 0, stream>>>(Bf, W_chi, chi);
    k_node2<<<NN, 64, 0, stream>>>(pos, ntype, src, shifts, Wemb, freqs, W_rt,
                                   W_Ar, W_mem, offs, indeg, elist, chi, A, B2f);
    k_mlp<<<(NN + 63)/64, 256, 0, stream>>>(Bf, B2f, W1, b1, W2, b2, W3, b3,
                                            batch, (float*)d_out);
}

// Round 7
// 368.821 us; speedup vs baseline: 1.5083x; 1.1207x over previous
//
#include <hip/hip_runtime.h>
#include <hip/hip_bf16.h>
#include <math.h>

#define NE 80000
#define NN 10000
#define NG 16
#define MP_NORM 0.31622776601683794f   // 1/sqrt(10)
#define RBF_NORM 0.60302268915552724f  // sqrt(2/5.5)

// monomial tables: index -> (lx,ly,lz), l
__constant__ int c_mx[20] = {0, 1,0,0, 2,1,1,0,0,0, 3,2,2,1,1,1,0,0,0,0};
__constant__ int c_my[20] = {0, 0,1,0, 0,1,0,2,1,0, 0,1,0,2,1,0,3,2,1,0};
__constant__ int c_mz[20] = {0, 0,0,1, 0,0,1,0,1,2, 0,0,1,0,1,2,0,1,2,3};

__device__ __forceinline__ int l_of_a(int a) {
    return (a >= 10) ? 3 : ((a >= 4) ? 2 : ((a >= 1) ? 1 : 0));
}

// symmetrize one node's 1080-vector (in LDS) -> 324 outputs (global row)
__device__ __forceinline__ void symm_from_lds(const float* Als, float* brow,
                                              int lane) {
    if (lane >= 54) return;
    const int s2 = lane / 9, c = lane - s2 * 9;
    const float* a = Als + s2 * 180 + c;
    float v[20];
    #pragma unroll
    for (int i = 0; i < 20; i++) v[i] = a[i * 9];
    const float o0 = v[0];
    const float o1 = v[1]*v[1] + v[2]*v[2] + v[3]*v[3];
    const float o2 = v[4]*v[4] + 2.f*v[5]*v[5] + 2.f*v[6]*v[6]
                   + v[7]*v[7] + 2.f*v[8]*v[8] + v[9]*v[9];
    const float o3 = v[10]*v[10] + 3.f*v[11]*v[11] + 3.f*v[12]*v[12]
                   + 3.f*v[13]*v[13] + 6.f*v[14]*v[14] + 3.f*v[15]*v[15]
                   + v[16]*v[16] + 3.f*v[17]*v[17] + 3.f*v[18]*v[18] + v[19]*v[19];
    const float o4 = v[1]*v[1]*v[4] + 2.f*v[1]*v[2]*v[5] + 2.f*v[1]*v[3]*v[6]
                   + 2.f*v[2]*v[1]*v[5] + v[2]*v[2]*v[7] + 2.f*v[2]*v[3]*v[8]
                   + 2.f*v[3]*v[1]*v[6] + 2.f*v[3]*v[2]*v[8] + v[3]*v[3]*v[9];
    const float o5 =
        v[1]*(v[4]*v[10] + 3.f*v[5]*v[11] + 3.f*v[6]*v[12] + 3.f*v[7]*v[13]
              + 6.f*v[8]*v[14] + 3.f*v[9]*v[15])
      + v[2]*(3.f*v[4]*v[11] + 3.f*v[5]*v[13] + 6.f*v[6]*v[14] + v[7]*v[16]
              + 3.f*v[8]*v[17] + 3.f*v[9]*v[18])
      + v[3]*(3.f*v[4]*v[12] + 6.f*v[5]*v[14] + 3.f*v[6]*v[15] + 3.f*v[7]*v[17]
              + 3.f*v[8]*v[18] + v[9]*v[19]);
    float* b = brow + s2 * 54 + c;
    b[0]  = o0;
    b[9]  = o1;
    b[18] = o2;
    b[27] = o3;
    b[36] = o4;
    b[45] = o5;
}

// ---------------------------------------------------------------------------
// CSR build: histogram of dst over fc-active edges, scan, fill.
// ---------------------------------------------------------------------------
__global__ __launch_bounds__(256) void k_hist(
    const float* __restrict__ pos, const int* __restrict__ src,
    const int* __restrict__ dst, const float* __restrict__ shifts,
    int* __restrict__ indeg)
{
    const int e = blockIdx.x * 256 + threadIdx.x;
    if (e >= NE) return;
    const int sn = src[e], dn = dst[e];
    const float vx = pos[3*dn+0] - pos[3*sn+0] + shifts[3*e+0];
    const float vy = pos[3*dn+1] - pos[3*sn+1] + shifts[3*e+1];
    const float vz = pos[3*dn+2] - pos[3*sn+2] + shifts[3*e+2];
    const float r = sqrtf(vx*vx + vy*vy + vz*vz) + 1e-9f;
    if (r * (1.0f / 5.5f) < 1.0f) atomicAdd(&indeg[dn], 1);
}

__global__ __launch_bounds__(256) void k_scan(const int* __restrict__ indeg,
                                              int* __restrict__ offs)
{
    __shared__ int part[256];
    const int t = threadIdx.x;
    int s = 0;
    for (int i = t * 40; i < t * 40 + 40; i++)
        if (i < NN) s += indeg[i];
    part[t] = s;
    __syncthreads();
    if (t == 0) {
        int run = 0;
        for (int i = 0; i < 256; i++) { int v = part[i]; part[i] = run; run += v; }
    }
    __syncthreads();
    int run = part[t];
    for (int i = t * 40; i < t * 40 + 40; i++) {
        if (i < NN) { offs[i] = run; run += indeg[i]; }
    }
}

__global__ __launch_bounds__(256) void k_fill(
    const float* __restrict__ pos, const int* __restrict__ src,
    const int* __restrict__ dst, const float* __restrict__ shifts,
    const int* __restrict__ offs, int* __restrict__ cursor,
    int* __restrict__ elist)
{
    const int e = blockIdx.x * 256 + threadIdx.x;
    if (e >= NE) return;
    const int sn = src[e], dn = dst[e];
    const float vx = pos[3*dn+0] - pos[3*sn+0] + shifts[3*e+0];
    const float vy = pos[3*dn+1] - pos[3*sn+1] + shifts[3*e+1];
    const float vz = pos[3*dn+2] - pos[3*sn+2] + shifts[3*e+2];
    const float r = sqrtf(vx*vx + vy*vy + vz*vz) + 1e-9f;
    if (r * (1.0f / 5.5f) < 1.0f) {
        const int p = offs[dn] + atomicAdd(&cursor[dn], 1);
        elist[p] = e;
    }
}

// ---------------------------------------------------------------------------
// Pass 1, gather form: one wave per node, one-edge-ahead prefetch of
// pos/shifts/ntype. Accumulate A[n] in registers, symmetrize inline -> B.
// ---------------------------------------------------------------------------
__global__ __launch_bounds__(64) void k_node1(
    const float* __restrict__ pos, const int* __restrict__ ntype,
    const int* __restrict__ srcArr, const float* __restrict__ shifts,
    const float* __restrict__ Wemb, const float* __restrict__ freqs,
    const float* __restrict__ W_rt, const int* __restrict__ offs,
    const int* __restrict__ indeg, const int* __restrict__ elist,
    float* __restrict__ A, float* __restrict__ Bf)
{
    __shared__ float eS[80];     // ang[0..19], code[20..28], radt[29..52]
    __shared__ float Als[1080];
    const int n = blockIdx.x, lane = threadIdx.x;
    int ridx[17], aidx[17], cidx[17];
    float acc[17];
    #pragma unroll
    for (int k = 0; k < 17; k++) {
        acc[k] = 0.f;
        const int i = lane + 64 * k;
        const int ii = (i < 1080) ? i : 0;
        const int s2 = ii / 180, rem = ii - s2 * 180;
        const int a = rem / 9, c = rem - a * 9;
        ridx[k] = 29 + l_of_a(a) * 6 + s2; aidx[k] = a; cidx[k] = 20 + c;
    }
    const float px = pos[3*n], py = pos[3*n+1], pz = pos[3*n+2];
    const float ed0 = Wemb[3*ntype[n]], ed1 = Wemb[3*ntype[n]+1],
                ed2 = Wemb[3*ntype[n]+2];
    float fr[6];
    #pragma unroll
    for (int q = 0; q < 6; q++) fr[q] = freqs[q];
    float wrt[6];
    if (lane >= 32 && lane < 56) {
        const int j = lane - 32, l = j / 6, s2 = j % 6;
        #pragma unroll
        for (int q = 0; q < 6; q++) wrt[q] = W_rt[(l*6 + q)*6 + s2];
    }
    const int e0 = offs[n], cnt = indeg[n];
    int e_n = 0, sn_n = 0, tn_n = 0;
    float pnx = 0, pny = 0, pnz = 0, snx = 0, sny = 0, snz = 0;
    if (cnt > 0) {
        e_n = elist[e0]; sn_n = srcArr[e_n]; tn_n = ntype[sn_n];
        pnx = pos[3*sn_n]; pny = pos[3*sn_n+1]; pnz = pos[3*sn_n+2];
        snx = shifts[3*e_n]; sny = shifts[3*e_n+1]; snz = shifts[3*e_n+2];
    }
    for (int t = 0; t < cnt; t++) {
        const int tn = tn_n;
        const float vx = px - pnx + snx;
        const float vy = py - pny + sny;
        const float vz = pz - pnz + snz;
        if (t + 1 < cnt) {
            e_n = elist[e0 + t + 1]; sn_n = srcArr[e_n]; tn_n = ntype[sn_n];
            pnx = pos[3*sn_n]; pny = pos[3*sn_n+1]; pnz = pos[3*sn_n+2];
            snx = shifts[3*e_n]; sny = shifts[3*e_n+1]; snz = shifts[3*e_n+2];
        }
        const float r = sqrtf(vx*vx + vy*vy + vz*vz) + 1e-9f;
        const float u = r * (1.0f / 5.5f);
        const float u2 = u*u, u3 = u2*u, u6 = u3*u3;
        const float fcv = 1.0f - 28.0f*u6 + 48.0f*u6*u - 21.0f*u6*u2;
        const float inv = 1.0f / r;
        float rb[6];
        #pragma unroll
        for (int q = 0; q < 6; q++)
            rb[q] = RBF_NORM * __sinf(r * fr[q]) * inv * fcv;
        if (lane < 20) {
            const float ux = vx*inv, uy = vy*inv, uz = vz*inv;
            const int lx = c_mx[lane], ly = c_my[lane], lz = c_mz[lane];
            float v = 1.f;
            for (int i = 0; i < lx; i++) v *= ux;
            for (int i = 0; i < ly; i++) v *= uy;
            for (int i = 0; i < lz; i++) v *= uz;
            eS[lane] = v;
        } else if (lane < 29) {
            const int c = lane - 20, m = c % 3;
            const float ed = (m == 0) ? ed0 : ((m == 1) ? ed1 : ed2);
            eS[lane] = Wemb[3*tn + c/3] * ed;
        } else if (lane >= 32 && lane < 56) {
            float s = 0.f;
            #pragma unroll
            for (int q = 0; q < 6; q++) s += rb[q] * wrt[q];
            eS[lane - 3] = s;
        }
        __syncthreads();
        #pragma unroll
        for (int k = 0; k < 17; k++)
            acc[k] += eS[ridx[k]] * eS[aidx[k]] * eS[cidx[k]];
        __syncthreads();
    }
    #pragma unroll
    for (int k = 0; k < 17; k++) {
        const int i = lane + 64 * k;
        if (i < 1080) { A[(long)n*1080 + i] = acc[k]; Als[i] = acc[k]; }
    }
    __syncthreads();
    symm_from_lds(Als, Bf + (long)n * 324, lane);
}

// chi[n,c'] = B[n,:] . W_chi[:,c']
__global__ __launch_bounds__(256) void k_chi(const float* __restrict__ Bf,
                                             const float* __restrict__ W_chi,
                                             float* __restrict__ chi)
{
    const int t = blockIdx.x * 256 + threadIdx.x;
    if (t >= NN * 9) return;
    const int cp = t % 9, n = t / 9;
    const float* b = Bf + (long)n * 324;
    float s = 0.f;
    #pragma unroll 4
    for (int j = 0; j < 324; j += 4) {
        const float4 bv = *(const float4*)(b + j);
        s += bv.x * W_chi[(j+0)*9 + cp] + bv.y * W_chi[(j+1)*9 + cp]
           + bv.z * W_chi[(j+2)*9 + cp] + bv.w * W_chi[(j+3)*9 + cp];
    }
    chi[t] = s;
}

// ---------------------------------------------------------------------------
// Pass 2, gather form with one-edge-ahead prefetch incl. A[src] row and chi.
// ---------------------------------------------------------------------------
__global__ __launch_bounds__(64) void k_node2(
    const float* __restrict__ pos, const int* __restrict__ ntype,
    const int* __restrict__ srcArr, const float* __restrict__ shifts,
    const float* __restrict__ Wemb, const float* __restrict__ freqs,
    const float* __restrict__ W_rt, const float* __restrict__ W_Ar,
    const float* __restrict__ W_mem, const int* __restrict__ offs,
    const int* __restrict__ indeg, const int* __restrict__ elist,
    const float* __restrict__ chi, const float* __restrict__ A,
    float* __restrict__ B2f)
{
    __shared__ float eS[80];     // ang, codechi[20..28], radtB[29..52], radtA[53..76]
    __shared__ float Als[1080];
    __shared__ float Qls[1080];
    __shared__ float Wm[144];
    const int n = blockIdx.x, lane = threadIdx.x;
    #pragma unroll
    for (int k = 0; k < 17; k++) {
        const int i = lane + 64 * k;
        if (i < 1080) Als[i] = A[(long)n*1080 + i];
    }
    Wm[lane] = W_mem[lane];
    Wm[lane + 64] = W_mem[lane + 64];
    if (lane < 16) Wm[lane + 128] = W_mem[lane + 128];
    int ridx[17], aidx[17], cidx[17];
    float acc[17];
    #pragma unroll
    for (int k = 0; k < 17; k++) {
        acc[k] = 0.f;
        const int i = lane + 64 * k;
        const int ii = (i < 1080) ? i : 0;
        const int s2 = ii / 180, rem = ii - s2 * 180;
        const int a = rem / 9, c = rem - a * 9;
        ridx[k] = 29 + l_of_a(a) * 6 + s2; aidx[k] = a; cidx[k] = 20 + c;
    }
    const float px = pos[3*n], py = pos[3*n+1], pz = pos[3*n+2];
    const float ed0 = Wemb[3*ntype[n]], ed1 = Wemb[3*ntype[n]+1],
                ed2 = Wemb[3*ntype[n]+2];
    float fr[6];
    #pragma unroll
    for (int q = 0; q < 6; q++) fr[q] = freqs[q];
    float wrtB[6], wrtA[6];
    if (lane >= 32 && lane < 56) {
        const int j = lane - 32, l = j / 6, s2 = j % 6;
        #pragma unroll
        for (int q = 0; q < 6; q++) {
            wrtB[q] = W_rt[(l*6 + q)*6 + s2];
            wrtA[q] = W_Ar[(l*6 + q)*6 + s2];
        }
    }
    __syncthreads();
    const int e0 = offs[n], cnt = indeg[n];
    int e_n = 0, sn_n = 0, tn_n = 0;
    float pnx = 0, pny = 0, pnz = 0, snx = 0, sny = 0, snz = 0, chin = 0.f;
    float an[17];
    #pragma unroll
    for (int k = 0; k < 17; k++) an[k] = 0.f;
    if (cnt > 0) {
        e_n = elist[e0]; sn_n = srcArr[e_n]; tn_n = ntype[sn_n];
        pnx = pos[3*sn_n]; pny = pos[3*sn_n+1]; pnz = pos[3*sn_n+2];
        snx = shifts[3*e_n]; sny = shifts[3*e_n+1]; snz = shifts[3*e_n+2];
        if (lane >= 20 && lane < 29) chin = chi[sn_n*9 + (lane - 20)];
        const float* ar = A + (long)sn_n * 1080;
        #pragma unroll
        for (int k = 0; k < 17; k++) {
            const int i = lane + 64 * k;
            if (i < 1080) an[k] = ar[i];
        }
    }
    for (int t = 0; t < cnt; t++) {
        const int tn = tn_n;
        const float chiv = chin;
        const float vx = px - pnx + snx;
        const float vy = py - pny + sny;
        const float vz = pz - pnz + snz;
        float av[17];
        #pragma unroll
        for (int k = 0; k < 17; k++) av[k] = an[k];
        if (t + 1 < cnt) {
            e_n = elist[e0 + t + 1]; sn_n = srcArr[e_n]; tn_n = ntype[sn_n];
            pnx = pos[3*sn_n]; pny = pos[3*sn_n+1]; pnz = pos[3*sn_n+2];
            snx = shifts[3*e_n]; sny = shifts[3*e_n+1]; snz = shifts[3*e_n+2];
            if (lane >= 20 && lane < 29) chin = chi[sn_n*9 + (lane - 20)];
            const float* ar = A + (long)sn_n * 1080;
            #pragma unroll
            for (int k = 0; k < 17; k++) {
                const int i = lane + 64 * k;
                if (i < 1080) an[k] = ar[i];
            }
        }
        const float r = sqrtf(vx*vx + vy*vy + vz*vz) + 1e-9f;
        const float u = r * (1.0f / 5.5f);
        const float u2 = u*u, u3 = u2*u, u6 = u3*u3;
        const float fcv = 1.0f - 28.0f*u6 + 48.0f*u6*u - 21.0f*u6*u2;
        const float inv = 1.0f / r;
        float rb[6];
        #pragma unroll
        for (int q = 0; q < 6; q++)
            rb[q] = RBF_NORM * __sinf(r * fr[q]) * inv * fcv;
        if (lane < 20) {
            const float ux = vx*inv, uy = vy*inv, uz = vz*inv;
            const int lx = c_mx[lane], ly = c_my[lane], lz = c_mz[lane];
            float v = 1.f;
            for (int i = 0; i < lx; i++) v *= ux;
            for (int i = 0; i < ly; i++) v *= uy;
            for (int i = 0; i < lz; i++) v *= uz;
            eS[lane] = v;
        } else if (lane < 29) {
            const int c = lane - 20, m = c % 3;
            const float ed = (m == 0) ? ed0 : ((m == 1) ? ed1 : ed2);
            eS[lane] = Wemb[3*tn + c/3] * ed * chiv;
        } else if (lane >= 32 && lane < 56) {
            float sB = 0.f, sA = 0.f;
            #pragma unroll
            for (int q = 0; q < 6; q++) { sB += rb[q]*wrtB[q]; sA += rb[q]*wrtA[q]; }
            eS[lane - 3]  = sB;
            eS[lane + 21] = sA;
        }
        __syncthreads();
        #pragma unroll
        for (int k = 0; k < 17; k++) {
            const int i = lane + 64 * k;
            if (i < 1080)
                acc[k] += eS[ridx[k]] * eS[aidx[k]] * eS[cidx[k]]
                        + av[k] * eS[ridx[k] + 24];
        }
        __syncthreads();
    }
    // memory term + MP_NORM -> Qls
    #pragma unroll
    for (int k = 0; k < 17; k++) {
        const int i = lane + 64 * k;
        if (i < 1080) {
            const int l6 = ridx[k] - 29;
            const int l = l6 / 6, s2v = l6 - 6 * l;
            const int rem = aidx[k] * 9 + (cidx[k] - 20);
            float m = 0.f;
            #pragma unroll
            for (int sp = 0; sp < 6; sp++)
                m += Als[sp*180 + rem] * Wm[l*36 + sp*6 + s2v];
            Qls[i] = acc[k] * MP_NORM + m;
        }
    }
    __syncthreads();
    symm_from_lds(Qls, B2f + (long)n * 324, lane);
}

// ---------------------------------------------------------------------------
// MLP readout v7: 1-wave blocks, 4 nodes per wave, lane = output column.
// feats (648/node) staged in small LDS (11 KB -> high occupancy, ~14 blk/CU);
// no barriers (single wave). Inner loop: 4 uniform ds_read_b128 (feats of 4
// nodes) + 4 coalesced W1 dword loads + 16 FMA per 4 K-steps. Layers 2/3 +
// segment-sum fused via shfl reduction.
// ---------------------------------------------------------------------------
__global__ __launch_bounds__(64) void k_mlp(
    const float* __restrict__ Bf, const float* __restrict__ B2f,
    const float* __restrict__ W1, const float* __restrict__ b1,
    const float* __restrict__ W2, const float* __restrict__ b2,
    const float* __restrict__ W3, const float* __restrict__ b3,
    const int* __restrict__ batch, float* __restrict__ out)
{
    __shared__ float F[4][648];      // [node][B(324) | B2(324)]
    __shared__ float h1L[4][64];
    const int lane = threadIdx.x;
    const int nb = blockIdx.x * 4;
    // stage feats, coalesced 256B loads
    #pragma unroll
    for (int nd = 0; nd < 4; nd++) {
        const float* bp  = Bf  + (long)(nb + nd) * 324;
        const float* b2p = B2f + (long)(nb + nd) * 324;
        #pragma unroll
        for (int j = 0; j < 5; j++) F[nd][j*64 + lane] = bp[j*64 + lane];
        if (lane < 4) F[nd][320 + lane] = bp[320 + lane];
        #pragma unroll
        for (int j = 0; j < 5; j++) F[nd][324 + j*64 + lane] = b2p[j*64 + lane];
        if (lane < 4) F[nd][644 + lane] = b2p[320 + lane];
    }
    // single wave: compiler's lgkmcnt ordering covers LDS write->read
    float a0 = 0.f, a1 = 0.f, a2 = 0.f, a3 = 0.f;
    // K permutation: k<324 -> W1 row 2k ; k>=324 -> row 2(k-324)+1.
    // 4*81 == 324, so each 4-k group lies in one half.
    #pragma unroll 2
    for (int k4 = 0; k4 < 162; k4++) {
        const float4 f0 = *(const float4*)&F[0][4*k4];
        const float4 f1 = *(const float4*)&F[1][4*k4];
        const float4 f2 = *(const float4*)&F[2][4*k4];
        const float4 f3 = *(const float4*)&F[3][4*k4];
        const int base = (k4 < 81) ? (8*k4) : (8*(k4 - 81) + 1);
        const float* wp = W1 + (size_t)base * 64 + lane;
        const float w0 = wp[0];
        const float w1 = wp[128];
        const float w2 = wp[256];
        const float w3 = wp[384];
        a0 += f0.x*w0 + f0.y*w1 + f0.z*w2 + f0.w*w3;
        a1 += f1.x*w0 + f1.y*w1 + f1.z*w2 + f1.w*w3;
        a2 += f2.x*w0 + f2.y*w1 + f2.z*w2 + f2.w*w3;
        a3 += f3.x*w0 + f3.y*w1 + f3.z*w2 + f3.w*w3;
    }
    const float bb1 = b1[lane];
    {
        float h;
        h = a0 + bb1; h1L[0][lane] = h / (1.f + __expf(-h));
        h = a1 + bb1; h1L[1][lane] = h / (1.f + __expf(-h));
        h = a2 + bb1; h1L[2][lane] = h / (1.f + __expf(-h));
        h = a3 + bb1; h1L[3][lane] = h / (1.f + __expf(-h));
    }
    // layers 2+3: two passes; in each, half-wave handles one node.
    const int oo = lane & 31;
    const float w3v = W3[oo];
    const float b2v = b2[oo];
    #pragma unroll
    for (int pass = 0; pass < 2; pass++) {
        const int nd = 2*pass + (lane >> 5);
        float g = b2v;
        #pragma unroll 8
        for (int k = 0; k < 64; k++)
            g = fmaf(h1L[nd][k], W2[k*32 + oo], g);
        g = g / (1.f + __expf(-g));
        float s = g * w3v;
        s += __shfl_xor(s, 16);
        s += __shfl_xor(s, 8);
        s += __shfl_xor(s, 4);
        s += __shfl_xor(s, 2);
        s += __shfl_xor(s, 1);
        if (oo == 0)
            atomicAdd(out + batch[nb + nd], s + b3[0]);
    }
}

extern "C" void kernel_launch(void* const* d_in, const int* in_sizes, int n_in,
                              void* d_out, int out_size, void* d_ws, size_t ws_size,
                              hipStream_t stream)
{
    const float* pos    = (const float*)d_in[0];
    const int*   ntype  = (const int*)  d_in[1];
    const int*   src    = (const int*)  d_in[2];
    const int*   dst    = (const int*)  d_in[3];
    const float* shifts = (const float*)d_in[4];
    const int*   batch  = (const int*)  d_in[5];
    const float* Wemb   = (const float*)d_in[6];
    const float* freqs  = (const float*)d_in[7];
    const float* W_rt   = (const float*)d_in[8];
    const float* W_mem  = (const float*)d_in[9];
    const float* W_Ar   = (const float*)d_in[10];
    const float* W_chi  = (const float*)d_in[11];
    const float* W1     = (const float*)d_in[12];
    const float* b1     = (const float*)d_in[13];
    const float* W2     = (const float*)d_in[14];
    const float* b2     = (const float*)d_in[15];
    const float* W3     = (const float*)d_in[16];
    const float* b3     = (const float*)d_in[17];

    float* ws   = (float*)d_ws;
    float* A    = ws;                        // [NN,1080]
    float* Bf   = A   + (size_t)NN * 1080;   // [NN,324]
    float* B2f  = Bf  + (size_t)NN * 324;    // [NN,324]
    float* chi  = B2f + (size_t)NN * 324;    // [NN,9]
    int*   indeg  = (int*)(chi + (size_t)NN * 9);
    int*   offs   = indeg  + 10240;
    int*   cursor = offs   + 10240;
    int*   elist  = cursor + 10240;          // [NE]

    hipMemsetAsync(indeg,  0, 10240 * sizeof(int), stream);
    hipMemsetAsync(cursor, 0, 10240 * sizeof(int), stream);
    hipMemsetAsync(d_out,  0, (size_t)out_size * sizeof(float), stream);

    k_hist<<<(NE + 255)/256, 256, 0, stream>>>(pos, src, dst, shifts, indeg);
    k_scan<<<1, 256, 0, stream>>>(indeg, offs);
    k_fill<<<(NE + 255)/256, 256, 0, stream>>>(pos, src, dst, shifts, offs,
                                               cursor, elist);
    k_node1<<<NN, 64, 0, stream>>>(pos, ntype, src, shifts, Wemb, freqs, W_rt,
                                   offs, indeg, elist, A, Bf);
    k_chi<<<(NN*9 + 255)/256, 256, 0, stream>>>(Bf, W_chi, chi);
    k_node2<<<NN, 64, 0, stream>>>(pos, ntype, src, shifts, Wemb, freqs, W_rt,
                                   W_Ar, W_mem, offs, indeg, elist, chi, A, B2f);
    k_mlp<<<NN/4, 64, 0, stream>>>(Bf, B2f, W1, b1, W2, b2, W3, b3,
                                   batch, (float*)d_out);
}